// Round 1
// baseline (3716.170 us; speedup 1.0000x reference)
//
#include <hip/hip_runtime.h>

typedef float f4 __attribute__((ext_vector_type(4)));

#define DI __device__ __forceinline__

DI f4 f4z() { f4 z = {0.f,0.f,0.f,0.f}; return z; }
DI f4 max4(f4 a, f4 b) {
    f4 r; r.x=fmaxf(a.x,b.x); r.y=fmaxf(a.y,b.y);
    r.z=fmaxf(a.z,b.z); r.w=fmaxf(a.w,b.w); return r;
}
DI f4 relu4(f4 a) { return max4(a, f4z()); }
DI float sigm(float x) { return 1.f/(1.f+expf(-x)); }

// ---------------------------------------------------------------------------
// conv0 (3->16, 3x3, pad1) + maxpool(3,s2,p1): [N,64,64,3]/255 -> [N,32,32,16]
// pooled tile 16x8 per block. grid = N*2*4, 256 thr.
// ---------------------------------------------------------------------------
__global__ __launch_bounds__(256) void k_conv0_pool(
    const float* __restrict__ x, const float* __restrict__ w,
    const float* __restrict__ bias, float* __restrict__ out)
{
    __shared__ __align__(16) float inL[35*22*3];
    __shared__ __align__(16) float wL[27*16];
    __shared__ __align__(16) float convL[33*20*16];
    const int tid = threadIdx.x;
    const int bid = blockIdx.x;
    const int n   = bid >> 3;
    const int pty = (bid >> 2) & 1;
    const int ptx = bid & 3;
    const int py0 = pty*16, px0 = ptx*8;
    const int cy0 = 2*py0 - 1, cx0 = 2*px0 - 1;

    for (int e = tid; e < 432; e += 256) {           // w: OIHW -> [tap][ci][co]
        int tap = e % 9, r = e / 9;
        int ci = r % 3, co = r / 3;
        wL[(tap*3 + ci)*16 + co] = w[e];
    }
    for (int e = tid; e < 35*22*3; e += 256) {
        int ci = e % 3, r = e / 3;
        int ix = r % 22, iy = r / 22;
        int gy = cy0 - 1 + iy, gx = cx0 - 1 + ix;
        float v = 0.f;
        if ((unsigned)gy < 64u && (unsigned)gx < 64u)
            v = x[((n*64 + gy)*64 + gx)*3 + ci] * (1.f/255.f);
        inL[e] = v;
    }
    __syncthreads();
    // conv phase: 33 rows x 5 x-groups x 4 co-groups = 660 items
    for (int it = tid; it < 660; it += 256) {
        const int cog = it & 3;
        const int pg  = it >> 2;
        const int xg  = pg % 5;
        const int ly  = pg / 5;
        const int x0  = xg*4, co0 = cog*4;
        f4 a0=f4z(), a1=f4z(), a2=f4z(), a3=f4z();
        #pragma unroll
        for (int ky = 0; ky < 3; ky++) {
            #pragma unroll
            for (int kx = 0; kx < 3; kx++) {
                const float* ip = &inL[((ly+ky)*22 + x0+kx)*3];
                #pragma unroll
                for (int ci = 0; ci < 3; ci++) {
                    f4 wv = *(const f4*)&wL[((ky*3+kx)*3 + ci)*16 + co0];
                    a0 += ip[0*3+ci]*wv;
                    a1 += ip[1*3+ci]*wv;
                    a2 += ip[2*3+ci]*wv;
                    a3 += ip[3*3+ci]*wv;
                }
            }
        }
        float* cp_ = &convL[(ly*20 + x0)*16 + co0];
        *(f4*)&cp_[0]  = a0;
        *(f4*)&cp_[16] = a1;
        *(f4*)&cp_[32] = a2;
        *(f4*)&cp_[48] = a3;
    }
    __syncthreads();
    for (int it = tid; it < 512; it += 256) {        // pool 16x8 x 16ch
        const int cog = it & 3;
        const int px  = it >> 2;
        const int lpx = px & 7, lpy = px >> 3;
        const int co0 = cog*4;
        f4 m = {-3e38f,-3e38f,-3e38f,-3e38f};
        #pragma unroll
        for (int dy = 0; dy < 3; dy++) {
            int ly = 2*lpy + dy;
            if ((unsigned)(cy0 + ly) >= 64u) continue;
            #pragma unroll
            for (int dx = 0; dx < 3; dx++) {
                int lx = 2*lpx + dx;
                if ((unsigned)(cx0 + lx) >= 64u) continue;
                m = max4(m, *(const f4*)&convL[(ly*20 + lx)*16 + co0]);
            }
        }
        m += *(const f4*)&bias[co0];
        int py = py0 + lpy, pxg = px0 + lpx;
        *(f4*)&out[((n*32 + py)*32 + pxg)*16 + co0] = m;
    }
}

// ---------------------------------------------------------------------------
// residual-block conv: out = conv3x3(relu(in)) + bias (+ res). NHWC, C=Cin=Cout
// thread = 4px x 4co, all-f4 LDS inner loop.
// ---------------------------------------------------------------------------
template<int C, int IMG, int TH, int TW, int NPB, bool ADD_RES>
__global__ __launch_bounds__(256) void k_conv_res(
    const float* __restrict__ in, const float* __restrict__ w,
    const float* __restrict__ bias, const float* __restrict__ res,
    float* __restrict__ out)
{
    constexpr int CP = C + 4;
    constexpr int IH = TH + 2, IW = TW + 2;
    constexpr int COGS = C/4;
    constexpr int XG = TW/4;
    constexpr int PGI = TH*XG;
    constexpr int TILES = (IMG/TH)*(IMG/TW);
    __shared__ __align__(16) float inL[NPB*IH*IW*CP];
    __shared__ __align__(16) float wL[9*C*C];
    const int tid = threadIdx.x;
    const int bid = blockIdx.x;
    const int n0  = (bid / TILES) * NPB;
    const int tt  = bid % TILES;
    const int ty0 = (tt / (IMG/TW)) * TH;
    const int tx0 = (tt % (IMG/TW)) * TW;

    for (int e = tid; e < 9*C*C; e += 256) {         // OIHW -> [tap][ci][co]
        int tap = e % 9, r = e / 9;
        int ci = r % C, co = r / C;
        wL[(tap*C + ci)*C + co] = w[e];
    }
    constexpr int E4 = NPB*IH*IW*(C/4);
    for (int e = tid; e < E4; e += 256) {
        int c4 = e % (C/4); int r = e / (C/4);
        int ix = r % IW; r /= IW;
        int iy = r % IH; int nl = r / IH;
        int gy = ty0 - 1 + iy, gx = tx0 - 1 + ix;
        f4 v = f4z();
        if ((unsigned)gy < (unsigned)IMG && (unsigned)gx < (unsigned)IMG)
            v = relu4(*(const f4*)&in[(((n0+nl)*IMG + gy)*IMG + gx)*C + c4*4]);
        *(f4*)&inL[((nl*IH + iy)*IW + ix)*CP + c4*4] = v;
    }
    __syncthreads();
    const int cog = tid % COGS, pg = tid / COGS;
    const int co0 = cog*4;
    const int nl  = pg / PGI;
    const int rr  = pg % PGI;
    const int y   = rr / XG;
    const int x0  = (rr % XG)*4;
    f4 acc[4] = {f4z(), f4z(), f4z(), f4z()};
    #pragma unroll
    for (int ky = 0; ky < 3; ky++) {
        #pragma unroll
        for (int kx = 0; kx < 3; kx++) {
            const float* ip = &inL[((nl*IH + y+ky)*IW + x0+kx)*CP];
            const float* wp = &wL[(ky*3+kx)*C*C + co0];
            #pragma unroll
            for (int cc = 0; cc < C; cc += 4) {
                f4 w0 = *(const f4*)&wp[(cc+0)*C];
                f4 w1 = *(const f4*)&wp[(cc+1)*C];
                f4 w2 = *(const f4*)&wp[(cc+2)*C];
                f4 w3 = *(const f4*)&wp[(cc+3)*C];
                #pragma unroll
                for (int p = 0; p < 4; p++) {
                    f4 iv = *(const f4*)&ip[p*CP + cc];
                    acc[p] += iv.x*w0;
                    acc[p] += iv.y*w1;
                    acc[p] += iv.z*w2;
                    acc[p] += iv.w*w3;
                }
            }
        }
    }
    const f4 bv = *(const f4*)&bias[co0];
    const int n = n0 + nl, py = ty0 + y, px = tx0 + x0;
    #pragma unroll
    for (int p = 0; p < 4; p++) {
        int off = ((n*IMG + py)*IMG + (px+p))*C + co0;
        f4 v = acc[p] + bv;
        if constexpr (ADD_RES) v += *(const f4*)&res[off];
        *(f4*)&out[off] = v;
    }
}

// ---------------------------------------------------------------------------
// conv3x3(pad1)+bias -> maxpool(3,s2,p1). NHWC. pooled tile PH x PW per block.
// ---------------------------------------------------------------------------
template<int CIN, int COUT, int IMG, int PH, int PW>
__global__ __launch_bounds__(256) void k_conv_pool(
    const float* __restrict__ in, const float* __restrict__ w,
    const float* __restrict__ bias, float* __restrict__ out)
{
    constexpr int OH  = IMG/2;
    constexpr int CRH = 2*PH+1, CVW = 2*PW+1;
    constexpr int XGC = (CVW+3)/4, CCW = XGC*4;
    constexpr int IH = CRH+2, IWW = CCW+2, CP = CIN+4;
    constexpr int PTX = OH/PW, PTY = OH/PH, TILES = PTY*PTX;
    __shared__ __align__(16) float inL[IH*IWW*CP];
    __shared__ __align__(16) float convL[CRH*CCW*COUT];
    __shared__ __align__(16) float wL[9*CIN*COUT];
    const int tid = threadIdx.x;
    const int bid = blockIdx.x;
    const int n  = bid / TILES;
    const int tt = bid % TILES;
    const int py0 = (tt / PTX)*PH, px0 = (tt % PTX)*PW;
    const int cy0 = 2*py0 - 1, cx0 = 2*px0 - 1;

    for (int e = tid; e < 9*CIN*COUT; e += 256) {
        int tap = e % 9, r = e / 9;
        int ci = r % CIN, co = r / CIN;
        wL[(tap*CIN + ci)*COUT + co] = w[e];
    }
    for (int e = tid; e < IH*IWW*(CIN/4); e += 256) {
        int c4 = e % (CIN/4); int r = e / (CIN/4);
        int ix = r % IWW; int iy = r / IWW;
        int gy = cy0 - 1 + iy, gx = cx0 - 1 + ix;
        f4 v = f4z();
        if ((unsigned)gy < (unsigned)IMG && (unsigned)gx < (unsigned)IMG)
            v = *(const f4*)&in[((n*IMG + gy)*IMG + gx)*CIN + c4*4];
        *(f4*)&inL[(iy*IWW + ix)*CP + c4*4] = v;
    }
    __syncthreads();
    constexpr int ITEMS = CRH*XGC*(COUT/4);
    for (int it = tid; it < ITEMS; it += 256) {
        const int cog = it % (COUT/4);
        const int pg  = it / (COUT/4);
        const int xg  = pg % XGC;
        const int ly  = pg / XGC;
        const int x0 = xg*4, co0 = cog*4;
        f4 acc[4] = {f4z(),f4z(),f4z(),f4z()};
        #pragma unroll
        for (int ky = 0; ky < 3; ky++) {
            #pragma unroll
            for (int kx = 0; kx < 3; kx++) {
                const float* ip = &inL[((ly+ky)*IWW + x0+kx)*CP];
                const float* wp = &wL[(ky*3+kx)*CIN*COUT + co0];
                #pragma unroll
                for (int cc = 0; cc < CIN; cc += 4) {
                    f4 w0 = *(const f4*)&wp[(cc+0)*COUT];
                    f4 w1 = *(const f4*)&wp[(cc+1)*COUT];
                    f4 w2 = *(const f4*)&wp[(cc+2)*COUT];
                    f4 w3 = *(const f4*)&wp[(cc+3)*COUT];
                    #pragma unroll
                    for (int p = 0; p < 4; p++) {
                        f4 iv = *(const f4*)&ip[p*CP + cc];
                        acc[p] += iv.x*w0;
                        acc[p] += iv.y*w1;
                        acc[p] += iv.z*w2;
                        acc[p] += iv.w*w3;
                    }
                }
            }
        }
        float* cp_ = &convL[(ly*CCW + x0)*COUT + co0];
        *(f4*)&cp_[0*COUT] = acc[0];
        *(f4*)&cp_[1*COUT] = acc[1];
        *(f4*)&cp_[2*COUT] = acc[2];
        *(f4*)&cp_[3*COUT] = acc[3];
    }
    __syncthreads();
    for (int it = tid; it < PH*PW*(COUT/4); it += 256) {
        const int cog = it % (COUT/4);
        const int px  = it / (COUT/4);
        const int lpx = px % PW, lpy = px / PW;
        const int co0 = cog*4;
        f4 m = {-3e38f,-3e38f,-3e38f,-3e38f};
        #pragma unroll
        for (int dy = 0; dy < 3; dy++) {
            int ly = 2*lpy + dy;
            if ((unsigned)(cy0 + ly) >= (unsigned)IMG) continue;
            #pragma unroll
            for (int dx = 0; dx < 3; dx++) {
                int lx = 2*lpx + dx;
                if ((unsigned)(cx0 + lx) >= (unsigned)IMG) continue;
                m = max4(m, *(const f4*)&convL[(ly*CCW + lx)*COUT + co0]);
            }
        }
        m += *(const f4*)&bias[co0];
        *(f4*)&out[((n*OH + py0+lpy)*OH + px0+lpx)*COUT + co0] = m;
    }
}

// ---------------------------------------------------------------------------
// GEMM: out[M,N] = op(A[M,K]) @ B[N,K]^T + bias. 64x64 tile, Kc=64.
// GATHER_B permutes B's K index (FC flatten NCHW order vs our NHWC z layout).
// ---------------------------------------------------------------------------
template<bool GATHER_B, bool RELU_A, bool RELU_OUT, bool TWO_BIAS>
__global__ __launch_bounds__(256) void k_gemm(
    const float* __restrict__ A, const float* __restrict__ Bm,
    const float* __restrict__ b1, const float* __restrict__ b2,
    float* __restrict__ out, int M, int N, int K)
{
    __shared__ __align__(16) float aL[64*72];
    __shared__ __align__(16) float bL[64*72];
    const int tid = threadIdx.x;
    const int nb = N >> 6;
    const int m0 = (blockIdx.x / nb) << 6;
    const int n0 = (blockIdx.x % nb) << 6;
    const int mt = tid & 15, nt = tid >> 4;
    f4 acc[4] = {f4z(),f4z(),f4z(),f4z()};
    for (int kc = 0; kc < K; kc += 64) {
        __syncthreads();
        #pragma unroll
        for (int i = 0; i < 16; i++) {
            int flat = i*256 + tid;
            int kk = flat & 63, mm = flat >> 6;
            float av = A[(m0+mm)*K + kc+kk];
            if (RELU_A) av = fmaxf(av, 0.f);
            aL[kk*72 + mm] = av;
            int kg = kc + kk;
            float bv;
            if constexpr (GATHER_B)
                bv = Bm[(n0+mm)*K + (kg & 31)*64 + (kg >> 5)];
            else
                bv = Bm[(n0+mm)*K + kg];
            bL[kk*72 + mm] = bv;
        }
        __syncthreads();
        #pragma unroll
        for (int k = 0; k < 64; k++) {
            f4 a4 = *(const f4*)&aL[k*72 + mt*4];
            f4 b4 = *(const f4*)&bL[k*72 + nt*4];
            acc[0] += a4.x * b4;
            acc[1] += a4.y * b4;
            acc[2] += a4.z * b4;
            acc[3] += a4.w * b4;
        }
    }
    f4 bias = *(const f4*)&b1[n0 + nt*4];
    if constexpr (TWO_BIAS) bias += *(const f4*)&b2[n0 + nt*4];
    #pragma unroll
    for (int mi = 0; mi < 4; mi++) {
        f4 v = acc[mi] + bias;
        if (RELU_OUT) v = relu4(v);
        *(f4*)&out[(m0 + mt*4 + mi)*N + n0 + nt*4] = v;
    }
}

// ---------------------------------------------------------------------------
// persistent LSTM: 64 WGs, WG owns 4 hidden units (all 4 gates, all 32 batch).
// gates = pre(+biases, precomputed) + h @ w_hh^T. one grid barrier per step.
// h double-buffered in global; c lives in LDS per WG.
// ---------------------------------------------------------------------------
__global__ __launch_bounds__(256) void k_lstm(
    const float* __restrict__ pre, const int* __restrict__ done,
    const float* __restrict__ h0, const float* __restrict__ c0,
    const float* __restrict__ whh,
    float* __restrict__ hbuf, unsigned* __restrict__ cnt,
    float* __restrict__ out)
{
    __shared__ __align__(16) float hLT[256*36];   // [k][b], padded
    __shared__ __align__(16) float wLT[256*20];   // [k][r], padded
    __shared__ __align__(16) float red[4096];
    __shared__ float gL[512];
    __shared__ float cL[128];
    __shared__ float mL[32];
    const int tid = threadIdx.x;
    const int j0 = blockIdx.x * 4;
    for (int e = tid; e < 4096; e += 256) {
        int r = e & 15, k = e >> 4;
        int rg = (r >> 2)*256 + j0 + (r & 3);      // r = gate*4 + jl
        wLT[k*20 + r] = whh[rg*256 + k];
    }
    if (tid < 128) cL[tid] = c0[(tid >> 2)*256 + j0 + (tid & 3)];
    const int bt = tid & 7, rt = (tid >> 3) & 3, ks = tid >> 5;
    for (int st = 0; st < 64; st++) {
        __syncthreads();
        if (tid < 32) mL[tid] = 1.f - (float)done[st*32 + tid];
        __syncthreads();
        const float* hsrc = (st == 0) ? h0 : (hbuf + (st & 1)*8192);
        for (int e = tid; e < 2048; e += 256) {    // stage h (masked, transposed)
            int b = e & 31, k4 = e >> 5;
            float mm = mL[b];
            f4 v = *(const f4*)&hsrc[b*256 + k4*4];
            hLT[(k4*4+0)*36 + b] = v.x*mm;
            hLT[(k4*4+1)*36 + b] = v.y*mm;
            hLT[(k4*4+2)*36 + b] = v.z*mm;
            hLT[(k4*4+3)*36 + b] = v.w*mm;
        }
        if (tid < 128) cL[tid] *= mL[tid >> 2];
        __syncthreads();
        f4 acc[4] = {f4z(),f4z(),f4z(),f4z()};     // 4r x 4b, k-slice of 32
        #pragma unroll
        for (int kk = 0; kk < 32; kk++) {
            int k = ks*32 + kk;
            f4 w4 = *(const f4*)&wLT[k*20 + rt*4];
            f4 h4 = *(const f4*)&hLT[k*36 + bt*4];
            acc[0] += w4.x * h4;
            acc[1] += w4.y * h4;
            acc[2] += w4.z * h4;
            acc[3] += w4.w * h4;
        }
        {
            f4* rp = (f4*)&red[((ks*32) + rt*8 + bt)*16];
            rp[0] = acc[0]; rp[1] = acc[1]; rp[2] = acc[2]; rp[3] = acc[3];
        }
        __syncthreads();
        #pragma unroll
        for (int o2 = 0; o2 < 2; o2++) {           // k-slice reduce + add pre
            int o = tid*2 + o2;
            int r = o >> 5, b = o & 31;
            int tl = (r >> 2)*8 + (b >> 2);
            int e = (r & 3)*4 + (b & 3);
            float s = 0.f;
            #pragma unroll
            for (int q = 0; q < 8; q++) s += red[(q*32 + tl)*16 + e];
            s += pre[(st*32 + b)*1024 + (r >> 2)*256 + j0 + (r & 3)];
            gL[o] = s;
        }
        __syncthreads();
        if (tid < 128) {                           // cell update, h out
            int b = tid >> 2, jl = tid & 3;
            float iv = gL[(jl     )*32 + b];
            float fv = gL[(4 + jl )*32 + b];
            float gv = gL[(8 + jl )*32 + b];
            float ov = gL[(12 + jl)*32 + b];
            float c = sigm(fv)*cL[tid] + sigm(iv)*tanhf(gv);
            cL[tid] = c;
            float h = sigm(ov)*tanhf(c);
            hbuf[((st+1) & 1)*8192 + b*256 + j0 + jl] = h;
            out[(st*32 + b)*256 + j0 + jl] = h;
        }
        __syncthreads();
        if (st < 63) {                             // grid barrier
            if (tid == 0) {
                __threadfence();
                __hip_atomic_fetch_add(&cnt[st], 1u, __ATOMIC_RELEASE, __HIP_MEMORY_SCOPE_AGENT);
                while (__hip_atomic_load(&cnt[st], __ATOMIC_ACQUIRE, __HIP_MEMORY_SCOPE_AGENT) < 64u) {
                    __builtin_amdgcn_s_sleep(4);
                }
                __threadfence();
            }
            __syncthreads();
        }
    }
}

// ---------------------------------------------------------------------------
extern "C" void kernel_launch(void* const* d_in, const int* in_sizes, int n_in,
                              void* d_out, int out_size, void* d_ws, size_t ws_size,
                              hipStream_t stream)
{
    (void)in_sizes; (void)n_in; (void)out_size; (void)ws_size;
    const float* x   = (const float*)d_in[0];
    const int*   dn  = (const int*)  d_in[1];
    const float* h0  = (const float*)d_in[2];
    const float* c0  = (const float*)d_in[3];
    const float* cw0 = (const float*)d_in[4];
    const float* cb0 = (const float*)d_in[5];
    const float* rw0 = (const float*)d_in[6];
    const float* rb0 = (const float*)d_in[7];
    const float* cw1 = (const float*)d_in[8];
    const float* cb1 = (const float*)d_in[9];
    const float* rw1 = (const float*)d_in[10];
    const float* rb1 = (const float*)d_in[11];
    const float* cw2 = (const float*)d_in[12];
    const float* cb2 = (const float*)d_in[13];
    const float* rw2 = (const float*)d_in[14];
    const float* rb2 = (const float*)d_in[15];
    const float* fcw = (const float*)d_in[16];
    const float* fcb = (const float*)d_in[17];
    const float* wih = (const float*)d_in[18];
    const float* whh = (const float*)d_in[19];
    const float* bih = (const float*)d_in[20];
    const float* bhh = (const float*)d_in[21];

    char* wsb = (char*)d_ws;
    // region A: [0, 134MB)   region B: [134MB, 268MB)
    float* P0   = (float*)wsb;                                  // seq0 main  [2048,32,32,16]
    float* T0   = (float*)(wsb + (size_t)134217728);            // seq0 temp
    float* P1   = T0;                                           // seq1 main  [2048,16,16,32]
    float* T1   = P0;                                           // seq1 temp
    float* P2   = P0;                                           // seq2 main  [2048,8,8,32]
    float* T2   = (float*)(wsb + (size_t)33554432);             // seq2 temp
    float* hid  = T0;                                           // [2048,256]
    float* preb = (float*)(wsb + (size_t)134217728 + 4194304);  // [2048,1024]
    float* hbuf = (float*)(wsb + (size_t)134217728 + 16777216); // 2x[32,256]
    unsigned* cnt = (unsigned*)(wsb + (size_t)134217728 + 16777216 + 65536);

    // ---- seq0: conv0+pool, 2 res blocks (C=16, img 32) ----
    k_conv0_pool<<<dim3(16384), dim3(256), 0, stream>>>(x, cw0, cb0, P0);
    k_conv_res<16,32,16,16,1,false><<<dim3(8192), dim3(256), 0, stream>>>(P0, rw0,        rb0,    nullptr, T0);
    k_conv_res<16,32,16,16,1,true ><<<dim3(8192), dim3(256), 0, stream>>>(T0, rw0+2304,   rb0+16, P0,      P0);
    k_conv_res<16,32,16,16,1,false><<<dim3(8192), dim3(256), 0, stream>>>(P0, rw0+2*2304, rb0+32, nullptr, T0);
    k_conv_res<16,32,16,16,1,true ><<<dim3(8192), dim3(256), 0, stream>>>(T0, rw0+3*2304, rb0+48, P0,      P0);
    // ---- seq1: conv+pool (16->32, img32->16), 2 res blocks (C=32, img 16) ----
    k_conv_pool<16,32,32,8,4><<<dim3(16384), dim3(256), 0, stream>>>(P0, cw1, cb1, P1);
    k_conv_res<32,16,16,8,1,false><<<dim3(4096), dim3(256), 0, stream>>>(P1, rw1,        rb1,    nullptr, T1);
    k_conv_res<32,16,16,8,1,true ><<<dim3(4096), dim3(256), 0, stream>>>(T1, rw1+9216,   rb1+32, P1,      P1);
    k_conv_res<32,16,16,8,1,false><<<dim3(4096), dim3(256), 0, stream>>>(P1, rw1+2*9216, rb1+64, nullptr, T1);
    k_conv_res<32,16,16,8,1,true ><<<dim3(4096), dim3(256), 0, stream>>>(T1, rw1+3*9216, rb1+96, P1,      P1);
    // ---- seq2: conv+pool (32->32, img16->8), 2 res blocks (C=32, img 8) ----
    k_conv_pool<32,32,16,8,4><<<dim3(4096), dim3(256), 0, stream>>>(P1, cw2, cb2, P2);
    k_conv_res<32,8,8,8,2,false><<<dim3(1024), dim3(256), 0, stream>>>(P2, rw2,        rb2,    nullptr, T2);
    k_conv_res<32,8,8,8,2,true ><<<dim3(1024), dim3(256), 0, stream>>>(T2, rw2+9216,   rb2+32, P2,      P2);
    k_conv_res<32,8,8,8,2,false><<<dim3(1024), dim3(256), 0, stream>>>(P2, rw2+2*9216, rb2+64, nullptr, T2);
    k_conv_res<32,8,8,8,2,true ><<<dim3(1024), dim3(256), 0, stream>>>(T2, rw2+3*9216, rb2+96, P2,      P2);
    // ---- FC: hidden = relu(relu(flat) @ fcw^T + fcb) ----
    k_gemm<true,true,true,false><<<dim3(128), dim3(256), 0, stream>>>(P2, fcw, fcb, nullptr, hid, 2048, 256, 2048);
    // ---- LSTM input projection: pre = hidden @ wih^T + bih + bhh ----
    k_gemm<false,false,false,true><<<dim3(512), dim3(256), 0, stream>>>(hid, wih, bih, bhh, preb, 2048, 1024, 256);
    // ---- recurrent LSTM ----
    hipMemsetAsync(cnt, 0, 256, stream);
    k_lstm<<<dim3(64), dim3(256), 0, stream>>>(preb, dn, h0, c0, whh, hbuf, cnt, (float*)d_out);
}

// Round 2
// 1937.552 us; speedup vs baseline: 1.9180x; 1.9180x over previous
//
#include <hip/hip_runtime.h>

typedef float f4 __attribute__((ext_vector_type(4)));
typedef short s8v __attribute__((ext_vector_type(8)));
typedef unsigned short u16;
typedef u16 u16x4 __attribute__((ext_vector_type(4)));
typedef u16 u16x8 __attribute__((ext_vector_type(8)));

#define DI __device__ __forceinline__

DI f4 f4z() { f4 z = {0.f,0.f,0.f,0.f}; return z; }
DI f4 max4(f4 a, f4 b) {
    f4 r; r.x=fmaxf(a.x,b.x); r.y=fmaxf(a.y,b.y);
    r.z=fmaxf(a.z,b.z); r.w=fmaxf(a.w,b.w); return r;
}
DI f4 relu4(f4 a) { return max4(a, f4z()); }
DI float sigm(float x) { return 1.f/(1.f+expf(-x)); }

DI u16 f2bf(float x) {                      // RNE float->bf16
    unsigned u = __builtin_bit_cast(unsigned, x);
    u += 0x7FFFu + ((u >> 16) & 1u);
    return (u16)(u >> 16);
}
DI float bf2f(u16 b) {
    unsigned u = ((unsigned)b) << 16;
    return __builtin_bit_cast(float, u);
}
DI f4 mfma16(s8v a, s8v b, f4 c) {
    return __builtin_amdgcn_mfma_f32_16x16x32_bf16(a, b, c, 0, 0, 0);
}

// ---------------------------------------------------------------------------
// conv0 (3->16, 3x3, pad1) + maxpool(3,s2,p1): [N,64,64,3]/255 -> [N,32,32,16]
// (unchanged from round 1 — fp32; Cin=3 is a poor MFMA shape)
// ---------------------------------------------------------------------------
__global__ __launch_bounds__(256) void k_conv0_pool(
    const float* __restrict__ x, const float* __restrict__ w,
    const float* __restrict__ bias, float* __restrict__ out)
{
    __shared__ __align__(16) float inL[35*22*3];
    __shared__ __align__(16) float wL[27*16];
    __shared__ __align__(16) float convL[33*20*16];
    const int tid = threadIdx.x;
    const int bid = blockIdx.x;
    const int n   = bid >> 3;
    const int pty = (bid >> 2) & 1;
    const int ptx = bid & 3;
    const int py0 = pty*16, px0 = ptx*8;
    const int cy0 = 2*py0 - 1, cx0 = 2*px0 - 1;

    for (int e = tid; e < 432; e += 256) {
        int tap = e % 9, r = e / 9;
        int ci = r % 3, co = r / 3;
        wL[(tap*3 + ci)*16 + co] = w[e];
    }
    for (int e = tid; e < 35*22*3; e += 256) {
        int ci = e % 3, r = e / 3;
        int ix = r % 22, iy = r / 22;
        int gy = cy0 - 1 + iy, gx = cx0 - 1 + ix;
        float v = 0.f;
        if ((unsigned)gy < 64u && (unsigned)gx < 64u)
            v = x[((n*64 + gy)*64 + gx)*3 + ci] * (1.f/255.f);
        inL[e] = v;
    }
    __syncthreads();
    for (int it = tid; it < 660; it += 256) {
        const int cog = it & 3;
        const int pg  = it >> 2;
        const int xg  = pg % 5;
        const int ly  = pg / 5;
        const int x0  = xg*4, co0 = cog*4;
        f4 a0=f4z(), a1=f4z(), a2=f4z(), a3=f4z();
        #pragma unroll
        for (int ky = 0; ky < 3; ky++) {
            #pragma unroll
            for (int kx = 0; kx < 3; kx++) {
                const float* ip = &inL[((ly+ky)*22 + x0+kx)*3];
                #pragma unroll
                for (int ci = 0; ci < 3; ci++) {
                    f4 wv = *(const f4*)&wL[((ky*3+kx)*3 + ci)*16 + co0];
                    a0 += ip[0*3+ci]*wv;
                    a1 += ip[1*3+ci]*wv;
                    a2 += ip[2*3+ci]*wv;
                    a3 += ip[3*3+ci]*wv;
                }
            }
        }
        float* cp_ = &convL[(ly*20 + x0)*16 + co0];
        *(f4*)&cp_[0]  = a0;
        *(f4*)&cp_[16] = a1;
        *(f4*)&cp_[32] = a2;
        *(f4*)&cp_[48] = a3;
    }
    __syncthreads();
    for (int it = tid; it < 512; it += 256) {
        const int cog = it & 3;
        const int px  = it >> 2;
        const int lpx = px & 7, lpy = px >> 3;
        const int co0 = cog*4;
        f4 m = {-3e38f,-3e38f,-3e38f,-3e38f};
        #pragma unroll
        for (int dy = 0; dy < 3; dy++) {
            int ly = 2*lpy + dy;
            if ((unsigned)(cy0 + ly) >= 64u) continue;
            #pragma unroll
            for (int dx = 0; dx < 3; dx++) {
                int lx = 2*lpx + dx;
                if ((unsigned)(cx0 + lx) >= 64u) continue;
                m = max4(m, *(const f4*)&convL[(ly*20 + lx)*16 + co0]);
            }
        }
        m += *(const f4*)&bias[co0];
        int py = py0 + lpy, pxg = px0 + lpx;
        *(f4*)&out[((n*32 + py)*32 + pxg)*16 + co0] = m;
    }
}

// ---------------------------------------------------------------------------
// bf16-MFMA conv3x3 pad1, NHWC. Trunk fp32 in/out; A/B rounded to bf16.
// Wave: B-frags (weights) in registers; per px-frag (4x4 px): 1 ds_read_b128
// per MFMA-K-step, NF=COUT/16 MFMAs per A read. D: col=lane&15(co),
// row=g*4+r(px) [m89 mapping]. K padded w/ zeroed B taps for CIN=16.
// ---------------------------------------------------------------------------
template<int CIN, int COUT, int IMG, int TH, int TW, int NPB,
         bool RELU_IN, bool ADD_RES, bool OUT_BF16>
__global__ __launch_bounds__(256) void k_conv_mfma(
    const float* __restrict__ in, const float* __restrict__ w,
    const float* __restrict__ bias, const float* __restrict__ res,
    float* __restrict__ outF, u16* __restrict__ outB)
{
    constexpr int CP  = CIN + 8;               // bf16 elems, 16B-aligned rows
    constexpr int IH  = TH + 2, WL = TW + 2;
    constexpr int KM  = (CIN == 16) ? 5 : 9;   // MFMA K-steps
    constexpr int KLD = KM * 32;               // staged K extent (zero-padded)
    constexpr int KPW = KLD + 8;               // wT row stride
    constexpr int NF  = COUT / 16;
    constexpr int FR  = TH / 4, FC = TW / 4;
    constexpr int NFRAG = NPB * FR * FC;
    constexpr int TY = IMG / TH, TX = IMG / TW, TILES = TY * TX;

    __shared__ __align__(16) u16 inL[NPB * IH * WL * CP];
    __shared__ __align__(16) u16 wT[COUT * KPW];

    const int tid = threadIdx.x;
    const int bid = blockIdx.x;
    const int n0 = (bid / TILES) * NPB;
    const int tt = bid % TILES;
    const int y0 = (tt / TX) * TH;
    const int x0 = (tt % TX) * TW;

    // stage weights: OIHW fp32 -> bf16 wT[co][tap*CIN+ci], zero K-pad
    for (int e = tid; e < COUT * KLD; e += 256) {
        int k = e % KLD, co = e / KLD;
        u16 bv = 0;
        if (k < 9 * CIN) {
            int tap = k / CIN, ci = k % CIN;
            bv = f2bf(w[(co * CIN + ci) * 9 + tap]);
        }
        wT[co * KPW + k] = bv;
    }
    // stage input tile (+halo) fp32 -> bf16 (optional ReLU)
    constexpr int SIT = NPB * IH * WL * (CIN / 4);
    for (int e = tid; e < SIT; e += 256) {
        int c4 = e % (CIN / 4); int r = e / (CIN / 4);
        int ix = r % WL; r /= WL;
        int iy = r % IH; int nl = r / IH;
        int gy = y0 - 1 + iy, gx = x0 - 1 + ix;
        f4 v = f4z();
        if ((unsigned)gy < (unsigned)IMG && (unsigned)gx < (unsigned)IMG) {
            v = *(const f4*)&in[(((n0 + nl) * IMG + gy) * IMG + gx) * CIN + c4 * 4];
            if (RELU_IN) v = relu4(v);
        }
        u16x4 b;
        b.x = f2bf(v.x); b.y = f2bf(v.y); b.z = f2bf(v.z); b.w = f2bf(v.w);
        *(u16x4*)&inL[((nl * IH + iy) * WL + ix) * CP + c4 * 4] = b;
    }
    __syncthreads();

    const int lane = tid & 63, wv = tid >> 6;
    const int p = lane & 15, g = lane >> 4;
    const int pr = p >> 2, pc = p & 3;

    // per-lane A k-group -> (ci0, spatial tap offset per K-step)
    int ci0;
    int aoff[KM];
    if constexpr (CIN == 32) {
        ci0 = g * 8;
        #pragma unroll
        for (int kk = 0; kk < KM; kk++)
            aoff[kk] = ((kk / 3) * WL + (kk % 3)) * CP;
    } else {
        ci0 = (g & 1) * 8;
        const int gh = g >> 1;
        #pragma unroll
        for (int kk = 0; kk < KM; kk++) {
            int t = 2 * kk + gh;
            if (t > 8) t = 8;                  // tap9 is zero in B; any valid A ok
            aoff[kk] = ((t / 3) * WL + (t % 3)) * CP;
        }
    }
    // weights -> registers (B frags), stationary for whole block tile
    s8v Bf[KM][NF];
    #pragma unroll
    for (int kk = 0; kk < KM; kk++)
        #pragma unroll
        for (int nf = 0; nf < NF; nf++)
            Bf[kk][nf] = *(const s8v*)&wT[(nf * 16 + p) * KPW + kk * 32 + g * 8];

    float bv_[NF];
    #pragma unroll
    for (int nf = 0; nf < NF; nf++) bv_[nf] = bias[nf * 16 + p];

    for (int f = wv; f < NFRAG; f += 4) {
        const int nl = f / (FR * FC);
        const int rem = f % (FR * FC);
        const int fr = rem / FC, fc = rem % FC;
        const int abase = ((nl * IH + fr * 4 + pr) * WL + fc * 4 + pc) * CP + ci0;
        f4 acc[NF];
        #pragma unroll
        for (int nf = 0; nf < NF; nf++) acc[nf] = f4z();
        #pragma unroll
        for (int kk = 0; kk < KM; kk++) {
            s8v a = *(const s8v*)&inL[abase + aoff[kk]];
            #pragma unroll
            for (int nf = 0; nf < NF; nf++)
                acc[nf] = mfma16(a, Bf[kk][nf], acc[nf]);
        }
        const int n = n0 + nl;
        const int gy = y0 + fr * 4 + g;        // D row = g*4+r -> px (g, r)
        #pragma unroll
        for (int nf = 0; nf < NF; nf++) {
            const int co = nf * 16 + p;
            #pragma unroll
            for (int r = 0; r < 4; r++) {
                const int gx = x0 + fc * 4 + r;
                const int idx = ((n * IMG + gy) * IMG + gx) * COUT + co;
                float vv = acc[nf][r] + bv_[nf];
                if constexpr (OUT_BF16) {
                    outB[idx] = f2bf(vv);
                } else {
                    if constexpr (ADD_RES) vv += res[idx];
                    outF[idx] = vv;
                }
            }
        }
    }
}

// ---------------------------------------------------------------------------
// maxpool 3x3 s2 p1 on bf16 conv output (bias already included) -> fp32 trunk
// ---------------------------------------------------------------------------
template<int S, int CO>
__global__ __launch_bounds__(256) void k_pool_b(
    const u16* __restrict__ in, float* __restrict__ out)
{
    constexpr int PS = S / 2;
    const int idx = blockIdx.x * 256 + threadIdx.x;
    int c8 = idx % (CO / 8); int r = idx / (CO / 8);
    const int px = r % PS; r /= PS;
    const int py = r % PS; const int n = r / PS;
    if (n >= 2048) return;
    float m[8];
    #pragma unroll
    for (int j = 0; j < 8; j++) m[j] = -3e38f;
    #pragma unroll
    for (int dy = 0; dy < 3; dy++) {
        const int y = 2 * py - 1 + dy;
        if ((unsigned)y >= (unsigned)S) continue;
        #pragma unroll
        for (int dx = 0; dx < 3; dx++) {
            const int x = 2 * px - 1 + dx;
            if ((unsigned)x >= (unsigned)S) continue;
            u16x8 v = *(const u16x8*)&in[((n * S + y) * S + x) * CO + c8 * 8];
            #pragma unroll
            for (int j = 0; j < 8; j++) m[j] = fmaxf(m[j], bf2f(v[j]));
        }
    }
    float* op = &out[((n * PS + py) * PS + px) * CO + c8 * 8];
    f4 o0 = {m[0], m[1], m[2], m[3]};
    f4 o1 = {m[4], m[5], m[6], m[7]};
    *(f4*)&op[0] = o0;
    *(f4*)&op[4] = o1;
}

// ---------------------------------------------------------------------------
// GEMM: out[M,N] = op(A[M,K]) @ B[N,K]^T + bias. 64x64 tile, Kc=64. (round 1)
// ---------------------------------------------------------------------------
template<bool GATHER_B, bool RELU_A, bool RELU_OUT, bool TWO_BIAS>
__global__ __launch_bounds__(256) void k_gemm(
    const float* __restrict__ A, const float* __restrict__ Bm,
    const float* __restrict__ b1, const float* __restrict__ b2,
    float* __restrict__ out, int M, int N, int K)
{
    __shared__ __align__(16) float aL[64*72];
    __shared__ __align__(16) float bL[64*72];
    const int tid = threadIdx.x;
    const int nb = N >> 6;
    const int m0 = (blockIdx.x / nb) << 6;
    const int n0 = (blockIdx.x % nb) << 6;
    const int mt = tid & 15, nt = tid >> 4;
    f4 acc[4] = {f4z(),f4z(),f4z(),f4z()};
    for (int kc = 0; kc < K; kc += 64) {
        __syncthreads();
        #pragma unroll
        for (int i = 0; i < 16; i++) {
            int flat = i*256 + tid;
            int kk = flat & 63, mm = flat >> 6;
            float av = A[(m0+mm)*K + kc+kk];
            if (RELU_A) av = fmaxf(av, 0.f);
            aL[kk*72 + mm] = av;
            int kg = kc + kk;
            float bv;
            if constexpr (GATHER_B)
                bv = Bm[(n0+mm)*K + (kg & 31)*64 + (kg >> 5)];
            else
                bv = Bm[(n0+mm)*K + kg];
            bL[kk*72 + mm] = bv;
        }
        __syncthreads();
        #pragma unroll
        for (int k = 0; k < 64; k++) {
            f4 a4 = *(const f4*)&aL[k*72 + mt*4];
            f4 b4 = *(const f4*)&bL[k*72 + nt*4];
            acc[0] += a4.x * b4;
            acc[1] += a4.y * b4;
            acc[2] += a4.z * b4;
            acc[3] += a4.w * b4;
        }
    }
    f4 bias = *(const f4*)&b1[n0 + nt*4];
    if constexpr (TWO_BIAS) bias += *(const f4*)&b2[n0 + nt*4];
    #pragma unroll
    for (int mi = 0; mi < 4; mi++) {
        f4 v = acc[mi] + bias;
        if (RELU_OUT) v = relu4(v);
        *(f4*)&out[(m0 + mt*4 + mi)*N + n0 + nt*4] = v;
    }
}

// ---------------------------------------------------------------------------
// persistent LSTM: 64 WGs, WG owns 4 hidden units. (round 1, verified)
// ---------------------------------------------------------------------------
__global__ __launch_bounds__(256) void k_lstm(
    const float* __restrict__ pre, const int* __restrict__ done,
    const float* __restrict__ h0, const float* __restrict__ c0,
    const float* __restrict__ whh,
    float* __restrict__ hbuf, unsigned* __restrict__ cnt,
    float* __restrict__ out)
{
    __shared__ __align__(16) float hLT[256*36];
    __shared__ __align__(16) float wLT[256*20];
    __shared__ __align__(16) float red[4096];
    __shared__ float gL[512];
    __shared__ float cL[128];
    __shared__ float mL[32];
    const int tid = threadIdx.x;
    const int j0 = blockIdx.x * 4;
    for (int e = tid; e < 4096; e += 256) {
        int r = e & 15, k = e >> 4;
        int rg = (r >> 2)*256 + j0 + (r & 3);
        wLT[k*20 + r] = whh[rg*256 + k];
    }
    if (tid < 128) cL[tid] = c0[(tid >> 2)*256 + j0 + (tid & 3)];
    const int bt = tid & 7, rt = (tid >> 3) & 3, ks = tid >> 5;
    for (int st = 0; st < 64; st++) {
        __syncthreads();
        if (tid < 32) mL[tid] = 1.f - (float)done[st*32 + tid];
        __syncthreads();
        const float* hsrc = (st == 0) ? h0 : (hbuf + (st & 1)*8192);
        for (int e = tid; e < 2048; e += 256) {
            int b = e & 31, k4 = e >> 5;
            float mm = mL[b];
            f4 v = *(const f4*)&hsrc[b*256 + k4*4];
            hLT[(k4*4+0)*36 + b] = v.x*mm;
            hLT[(k4*4+1)*36 + b] = v.y*mm;
            hLT[(k4*4+2)*36 + b] = v.z*mm;
            hLT[(k4*4+3)*36 + b] = v.w*mm;
        }
        if (tid < 128) cL[tid] *= mL[tid >> 2];
        __syncthreads();
        f4 acc[4] = {f4z(),f4z(),f4z(),f4z()};
        #pragma unroll
        for (int kk = 0; kk < 32; kk++) {
            int k = ks*32 + kk;
            f4 w4 = *(const f4*)&wLT[k*20 + rt*4];
            f4 h4 = *(const f4*)&hLT[k*36 + bt*4];
            acc[0] += w4.x * h4;
            acc[1] += w4.y * h4;
            acc[2] += w4.z * h4;
            acc[3] += w4.w * h4;
        }
        {
            f4* rp = (f4*)&red[((ks*32) + rt*8 + bt)*16];
            rp[0] = acc[0]; rp[1] = acc[1]; rp[2] = acc[2]; rp[3] = acc[3];
        }
        __syncthreads();
        #pragma unroll
        for (int o2 = 0; o2 < 2; o2++) {
            int o = tid*2 + o2;
            int r = o >> 5, b = o & 31;
            int tl = (r >> 2)*8 + (b >> 2);
            int e = (r & 3)*4 + (b & 3);
            float s = 0.f;
            #pragma unroll
            for (int q = 0; q < 8; q++) s += red[(q*32 + tl)*16 + e];
            s += pre[(st*32 + b)*1024 + (r >> 2)*256 + j0 + (r & 3)];
            gL[o] = s;
        }
        __syncthreads();
        if (tid < 128) {
            int b = tid >> 2, jl = tid & 3;
            float iv = gL[(jl     )*32 + b];
            float fv = gL[(4 + jl )*32 + b];
            float gv = gL[(8 + jl )*32 + b];
            float ov = gL[(12 + jl)*32 + b];
            float c = sigm(fv)*cL[tid] + sigm(iv)*tanhf(gv);
            cL[tid] = c;
            float h = sigm(ov)*tanhf(c);
            hbuf[((st+1) & 1)*8192 + b*256 + j0 + jl] = h;
            out[(st*32 + b)*256 + j0 + jl] = h;
        }
        __syncthreads();
        if (st < 63) {
            if (tid == 0) {
                __threadfence();
                __hip_atomic_fetch_add(&cnt[st], 1u, __ATOMIC_RELEASE, __HIP_MEMORY_SCOPE_AGENT);
                while (__hip_atomic_load(&cnt[st], __ATOMIC_ACQUIRE, __HIP_MEMORY_SCOPE_AGENT) < 64u) {
                    __builtin_amdgcn_s_sleep(4);
                }
                __threadfence();
            }
            __syncthreads();
        }
    }
}

// ---------------------------------------------------------------------------
extern "C" void kernel_launch(void* const* d_in, const int* in_sizes, int n_in,
                              void* d_out, int out_size, void* d_ws, size_t ws_size,
                              hipStream_t stream)
{
    (void)in_sizes; (void)n_in; (void)out_size; (void)ws_size;
    const float* x   = (const float*)d_in[0];
    const int*   dn  = (const int*)  d_in[1];
    const float* h0  = (const float*)d_in[2];
    const float* c0  = (const float*)d_in[3];
    const float* cw0 = (const float*)d_in[4];
    const float* cb0 = (const float*)d_in[5];
    const float* rw0 = (const float*)d_in[6];
    const float* rb0 = (const float*)d_in[7];
    const float* cw1 = (const float*)d_in[8];
    const float* cb1 = (const float*)d_in[9];
    const float* rw1 = (const float*)d_in[10];
    const float* rb1 = (const float*)d_in[11];
    const float* cw2 = (const float*)d_in[12];
    const float* cb2 = (const float*)d_in[13];
    const float* rw2 = (const float*)d_in[14];
    const float* rb2 = (const float*)d_in[15];
    const float* fcw = (const float*)d_in[16];
    const float* fcb = (const float*)d_in[17];
    const float* wih = (const float*)d_in[18];
    const float* whh = (const float*)d_in[19];
    const float* bih = (const float*)d_in[20];
    const float* bhh = (const float*)d_in[21];

    char* wsb = (char*)d_ws;
    float* P0 = (float*)wsb;                         // [2048,32,32,16] f32  128MiB
    float* T0 = (float*)(wsb + 134217728ull);        // [2048,32,32,16] f32
    u16*   C1 = (u16*)  (wsb + 134217728ull);        // [2048,32,32,32] bf16 (over T0, dead)
    float* P1 = (float*)wsb;                         // [2048,16,16,32] f32  64MiB
    float* T1 = (float*)(wsb + 67108864ull);
    u16*   C2 = (u16*)  (wsb + 134217728ull);        // [2048,16,16,32] bf16 32MiB
    float* P2 = (float*)wsb;                         // [2048,8,8,32] f32   16MiB
    float* T2 = (float*)(wsb + 16777216ull);
    float* hid  = (float*)(wsb + 33554432ull);       // [2048,256] f32
    float* preb = (float*)(wsb + 36700160ull);       // [2048,1024] f32
    float* hbuf = (float*)(wsb + 46137344ull);       // 2x[32,256] f32
    unsigned* cnt = (unsigned*)(wsb + 46268416ull);

    // seq0: conv0+pool (fp32), 2 res blocks (C=16, img32, MFMA)
    k_conv0_pool<<<dim3(16384), dim3(256), 0, stream>>>(x, cw0, cb0, P0);
    k_conv_mfma<16,16,32,16,32,1,true,false,false><<<dim3(4096), dim3(256), 0, stream>>>(P0, rw0,        rb0,    nullptr, T0, nullptr);
    k_conv_mfma<16,16,32,16,32,1,true,true ,false><<<dim3(4096), dim3(256), 0, stream>>>(T0, rw0+2304,   rb0+16, P0,      P0, nullptr);
    k_conv_mfma<16,16,32,16,32,1,true,false,false><<<dim3(4096), dim3(256), 0, stream>>>(P0, rw0+2*2304, rb0+32, nullptr, T0, nullptr);
    k_conv_mfma<16,16,32,16,32,1,true,true ,false><<<dim3(4096), dim3(256), 0, stream>>>(T0, rw0+3*2304, rb0+48, P0,      P0, nullptr);
    // seq1: conv1 (16->32, MFMA, bf16 out) + pool, 2 res blocks (C=32, img16)
    k_conv_mfma<16,32,32,16,32,1,false,false,true><<<dim3(4096), dim3(256), 0, stream>>>(P0, cw1, cb1, nullptr, nullptr, C1);
    k_pool_b<32,32><<<dim3(8192), dim3(256), 0, stream>>>(C1, P1);
    k_conv_mfma<32,32,16,16,16,1,true,false,false><<<dim3(2048), dim3(256), 0, stream>>>(P1, rw1,        rb1,    nullptr, T1, nullptr);
    k_conv_mfma<32,32,16,16,16,1,true,true ,false><<<dim3(2048), dim3(256), 0, stream>>>(T1, rw1+9216,   rb1+32, P1,      P1, nullptr);
    k_conv_mfma<32,32,16,16,16,1,true,false,false><<<dim3(2048), dim3(256), 0, stream>>>(P1, rw1+2*9216, rb1+64, nullptr, T1, nullptr);
    k_conv_mfma<32,32,16,16,16,1,true,true ,false><<<dim3(2048), dim3(256), 0, stream>>>(T1, rw1+3*9216, rb1+96, P1,      P1, nullptr);
    // seq2: conv2 (32->32, MFMA, bf16 out) + pool, 2 res blocks (C=32, img8)
    k_conv_mfma<32,32,16,16,16,1,false,false,true><<<dim3(2048), dim3(256), 0, stream>>>(P1, cw2, cb2, nullptr, nullptr, C2);
    k_pool_b<16,32><<<dim3(2048), dim3(256), 0, stream>>>(C2, P2);
    k_conv_mfma<32,32,8,8,8,4,true,false,false><<<dim3(512), dim3(256), 0, stream>>>(P2, rw2,        rb2,    nullptr, T2, nullptr);
    k_conv_mfma<32,32,8,8,8,4,true,true ,false><<<dim3(512), dim3(256), 0, stream>>>(T2, rw2+9216,   rb2+32, P2,      P2, nullptr);
    k_conv_mfma<32,32,8,8,8,4,true,false,false><<<dim3(512), dim3(256), 0, stream>>>(P2, rw2+2*9216, rb2+64, nullptr, T2, nullptr);
    k_conv_mfma<32,32,8,8,8,4,true,true ,false><<<dim3(512), dim3(256), 0, stream>>>(T2, rw2+3*9216, rb2+96, P2,      P2, nullptr);
    // FC + LSTM input projection + recurrent LSTM
    k_gemm<true,true,true,false><<<dim3(128), dim3(256), 0, stream>>>(P2, fcw, fcb, nullptr, hid, 2048, 256, 2048);
    k_gemm<false,false,false,true><<<dim3(512), dim3(256), 0, stream>>>(hid, wih, bih, bhh, preb, 2048, 1024, 256);
    hipMemsetAsync(cnt, 0, 256, stream);
    k_lstm<<<dim3(64), dim3(256), 0, stream>>>(preb, dn, h0, c0, whh, hbuf, cnt, (float*)d_out);
}

// Round 4
// 1769.380 us; speedup vs baseline: 2.1003x; 1.0950x over previous
//
#include <hip/hip_runtime.h>

typedef float f4 __attribute__((ext_vector_type(4)));
typedef short s8v __attribute__((ext_vector_type(8)));
typedef unsigned short u16;
typedef u16 u16x4 __attribute__((ext_vector_type(4)));
typedef u16 u16x8 __attribute__((ext_vector_type(8)));

#define DI __device__ __forceinline__

DI f4 f4z() { f4 z = {0.f,0.f,0.f,0.f}; return z; }
DI f4 max4(f4 a, f4 b) {
    f4 r; r.x=fmaxf(a.x,b.x); r.y=fmaxf(a.y,b.y);
    r.z=fmaxf(a.z,b.z); r.w=fmaxf(a.w,b.w); return r;
}
DI f4 relu4(f4 a) { return max4(a, f4z()); }
DI float sigm(float x) { return 1.f/(1.f+expf(-x)); }

DI u16 f2bf(float x) {                      // RNE float->bf16
    unsigned u = __builtin_bit_cast(unsigned, x);
    u += 0x7FFFu + ((u >> 16) & 1u);
    return (u16)(u >> 16);
}
DI float bf2f(u16 b) {
    unsigned u = ((unsigned)b) << 16;
    return __builtin_bit_cast(float, u);
}
DI f4 mfma16(s8v a, s8v b, f4 c) {
    return __builtin_amdgcn_mfma_f32_16x16x32_bf16(a, b, c, 0, 0, 0);
}

// ---------------------------------------------------------------------------
// conv0 MFMA: (3->16, 3x3, pad1) + maxpool(3,s2,p1). K = tap*4+ci (taps pad
// to 16, ci pad to 4 => K=64, 2 MFMA steps). M = 16 conv-x px per fragment.
// Block = 16x16 pooled tile (quarter image); conv region 33x33; grid N*4.
// ---------------------------------------------------------------------------
__global__ __launch_bounds__(256) void k_conv0_mfma(
    const float* __restrict__ x, const float* __restrict__ w,
    const float* __restrict__ bias, float* __restrict__ out)
{
    __shared__ __align__(16) u16 inS[36*36*4];     // input tile, ch pad 4
    __shared__ __align__(16) u16 wT[16*72];        // B: [co][k], k=tap*4+ci
    __shared__ __align__(16) u16 convL[33*34*16];  // conv out [y][x(pad34)][co]
    const int tid = threadIdx.x;
    const int bid = blockIdx.x;
    const int n = bid >> 2, q = bid & 3;
    const int py0 = (q >> 1) * 16, px0 = (q & 1) * 16;
    const int iy0 = 2*py0 - 2, ix0 = 2*px0 - 2;    // staged origin (abs input px)

    // weights OIHW[16,3,3,3] -> wT[co][tap*4+ci]; taps>=9, ci==3 zeroed
    for (int e = tid; e < 1024; e += 256) {
        const int k = e & 63, co = e >> 6;
        const int tap = k >> 2, ci = k & 3;
        u16 v = 0;
        if (tap < 9 && ci < 3) v = f2bf(w[(co*3 + ci)*9 + tap]);
        wT[co*72 + k] = v;
    }
    // stage input 36x36x4 bf16 (scaled 1/255, zero pad)
    for (int e = tid; e < 1296; e += 256) {
        const int ix = e % 36, iy = e / 36;
        const int gy = iy0 + iy, gx = ix0 + ix;
        u16x4 pk = {0,0,0,0};
        if ((unsigned)gy < 64u && (unsigned)gx < 64u) {
            const float* xp = &x[((n*64 + gy)*64 + gx)*3];
            pk.x = f2bf(xp[0] * (1.f/255.f));
            pk.y = f2bf(xp[1] * (1.f/255.f));
            pk.z = f2bf(xp[2] * (1.f/255.f));
        }
        *(u16x4*)&inS[(iy*36 + ix)*4] = pk;
    }
    __syncthreads();

    const int lane = tid & 63, wv = tid >> 6;
    const int p = lane & 15, g = lane >> 4;
    const s8v B0 = *(const s8v*)&wT[p*72 + g*8];
    const s8v B1 = *(const s8v*)&wT[p*72 + 32 + g*8];
    const int t0 = 2*g, t1 = 2*g + 1;              // taps for K-step 0
    const int dy0 = t0/3, dx0 = t0%3, dy1 = t1/3, dx1 = t1%3;

    // 33 conv rows x 3 x-strips (xb 0/16/32; strip-2 mostly discarded)
    for (int t = wv; t < 99; t += 4) {
        const int y = t / 3, xb = (t % 3) * 16;
        const int xr = xb + p;                     // this lane's conv x (M idx)
        const int ia = min(xr + dx0, 35), ib = min(xr + dx1, 35), ic = min(xr + 2, 35);
        u16x4 a0 = *(const u16x4*)&inS[((y + dy0)*36 + ia)*4];
        u16x4 a1 = *(const u16x4*)&inS[((y + dy1)*36 + ib)*4];
        u16x4 a2 = *(const u16x4*)&inS[((y + 2  )*36 + ic)*4];
        s8v A0, A1;
        A0[0]=a0.x; A0[1]=a0.y; A0[2]=a0.z; A0[3]=a0.w;
        A0[4]=a1.x; A0[5]=a1.y; A0[6]=a1.z; A0[7]=a1.w;
        A1[0]=a2.x; A1[1]=a2.y; A1[2]=a2.z; A1[3]=a2.w;   // tap8 (dy2,dx2)
        A1[4]=a2.x; A1[5]=a2.y; A1[6]=a2.z; A1[7]=a2.w;   // taps>=9: B rows 0
        f4 acc = mfma16(A0, B0, f4z());
        acc = mfma16(A1, B1, acc);
        #pragma unroll
        for (int r = 0; r < 4; r++) {              // D: row=g*4+r (px), col=p (co)
            const int xo = xb + g*4 + r;
            if (xo < 33) convL[(y*34 + xo)*16 + p] = f2bf(acc[r]);
        }
    }
    __syncthreads();
    // pool (3,s2,p1) over conv region, +bias, fp32 out
    for (int it = tid; it < 512; it += 256) {
        const int c8 = it & 1;
        const int pp = it >> 1;
        const int lpx = pp & 15, lpy = pp >> 4;
        float m[8];
        #pragma unroll
        for (int j = 0; j < 8; j++) m[j] = -3e38f;
        #pragma unroll
        for (int dy = 0; dy < 3; dy++) {
            const int ya = 2*(py0 + lpy) - 1 + dy;
            if ((unsigned)ya >= 64u) continue;
            const int yr = 2*lpy + dy;
            #pragma unroll
            for (int dx = 0; dx < 3; dx++) {
                const int xa = 2*(px0 + lpx) - 1 + dx;
                if ((unsigned)xa >= 64u) continue;
                const int xr = 2*lpx + dx;
                u16x8 v = *(const u16x8*)&convL[(yr*34 + xr)*16 + c8*8];
                #pragma unroll
                for (int j = 0; j < 8; j++) m[j] = fmaxf(m[j], bf2f(v[j]));
            }
        }
        f4 o0 = {m[0]+bias[c8*8+0], m[1]+bias[c8*8+1], m[2]+bias[c8*8+2], m[3]+bias[c8*8+3]};
        f4 o1 = {m[4]+bias[c8*8+4], m[5]+bias[c8*8+5], m[6]+bias[c8*8+6], m[7]+bias[c8*8+7]};
        float* op = &out[((n*32 + py0+lpy)*32 + px0+lpx)*16 + c8*8];
        *(f4*)&op[0] = o0;
        *(f4*)&op[4] = o1;
    }
}

// ---------------------------------------------------------------------------
// bf16-MFMA conv3x3 pad1, NHWC (validated round 2)
// ---------------------------------------------------------------------------
template<int CIN, int COUT, int IMG, int TH, int TW, int NPB,
         bool RELU_IN, bool ADD_RES, bool OUT_BF16>
__global__ __launch_bounds__(256) void k_conv_mfma(
    const float* __restrict__ in, const float* __restrict__ w,
    const float* __restrict__ bias, const float* __restrict__ res,
    float* __restrict__ outF, u16* __restrict__ outB)
{
    constexpr int CP  = CIN + 8;
    constexpr int IH  = TH + 2, WL = TW + 2;
    constexpr int KM  = (CIN == 16) ? 5 : 9;
    constexpr int KLD = KM * 32;
    constexpr int KPW = KLD + 8;
    constexpr int NF  = COUT / 16;
    constexpr int FR  = TH / 4, FC = TW / 4;
    constexpr int NFRAG = NPB * FR * FC;
    constexpr int TY = IMG / TH, TX = IMG / TW, TILES = TY * TX;

    __shared__ __align__(16) u16 inL[NPB * IH * WL * CP];
    __shared__ __align__(16) u16 wT[COUT * KPW];

    const int tid = threadIdx.x;
    const int bid = blockIdx.x;
    const int n0 = (bid / TILES) * NPB;
    const int tt = bid % TILES;
    const int y0 = (tt / TX) * TH;
    const int x0 = (tt % TX) * TW;

    for (int e = tid; e < COUT * KLD; e += 256) {
        int k = e % KLD, co = e / KLD;
        u16 bv = 0;
        if (k < 9 * CIN) {
            int tap = k / CIN, ci = k % CIN;
            bv = f2bf(w[(co * CIN + ci) * 9 + tap]);
        }
        wT[co * KPW + k] = bv;
    }
    constexpr int SIT = NPB * IH * WL * (CIN / 4);
    for (int e = tid; e < SIT; e += 256) {
        int c4 = e % (CIN / 4); int r = e / (CIN / 4);
        int ix = r % WL; r /= WL;
        int iy = r % IH; int nl = r / IH;
        int gy = y0 - 1 + iy, gx = x0 - 1 + ix;
        f4 v = f4z();
        if ((unsigned)gy < (unsigned)IMG && (unsigned)gx < (unsigned)IMG) {
            v = *(const f4*)&in[(((n0 + nl) * IMG + gy) * IMG + gx) * CIN + c4 * 4];
            if (RELU_IN) v = relu4(v);
        }
        u16x4 b;
        b.x = f2bf(v.x); b.y = f2bf(v.y); b.z = f2bf(v.z); b.w = f2bf(v.w);
        *(u16x4*)&inL[((nl * IH + iy) * WL + ix) * CP + c4 * 4] = b;
    }
    __syncthreads();

    const int lane = tid & 63, wv = tid >> 6;
    const int p = lane & 15, g = lane >> 4;
    const int pr = p >> 2, pc = p & 3;

    int ci0;
    int aoff[KM];
    if constexpr (CIN == 32) {
        ci0 = g * 8;
        #pragma unroll
        for (int kk = 0; kk < KM; kk++)
            aoff[kk] = ((kk / 3) * WL + (kk % 3)) * CP;
    } else {
        ci0 = (g & 1) * 8;
        const int gh = g >> 1;
        #pragma unroll
        for (int kk = 0; kk < KM; kk++) {
            int t = 2 * kk + gh;
            if (t > 8) t = 8;
            aoff[kk] = ((t / 3) * WL + (t % 3)) * CP;
        }
    }
    s8v Bf[KM][NF];
    #pragma unroll
    for (int kk = 0; kk < KM; kk++)
        #pragma unroll
        for (int nf = 0; nf < NF; nf++)
            Bf[kk][nf] = *(const s8v*)&wT[(nf * 16 + p) * KPW + kk * 32 + g * 8];

    float bv_[NF];
    #pragma unroll
    for (int nf = 0; nf < NF; nf++) bv_[nf] = bias[nf * 16 + p];

    for (int f = wv; f < NFRAG; f += 4) {
        const int nl = f / (FR * FC);
        const int rem = f % (FR * FC);
        const int fr = rem / FC, fc = rem % FC;
        const int abase = ((nl * IH + fr * 4 + pr) * WL + fc * 4 + pc) * CP + ci0;
        f4 acc[NF];
        #pragma unroll
        for (int nf = 0; nf < NF; nf++) acc[nf] = f4z();
        #pragma unroll
        for (int kk = 0; kk < KM; kk++) {
            s8v a = *(const s8v*)&inL[abase + aoff[kk]];
            #pragma unroll
            for (int nf = 0; nf < NF; nf++)
                acc[nf] = mfma16(a, Bf[kk][nf], acc[nf]);
        }
        const int n = n0 + nl;
        const int gy = y0 + fr * 4 + g;
        #pragma unroll
        for (int nf = 0; nf < NF; nf++) {
            const int co = nf * 16 + p;
            #pragma unroll
            for (int r = 0; r < 4; r++) {
                const int gx = x0 + fc * 4 + r;
                const int idx = ((n * IMG + gy) * IMG + gx) * COUT + co;
                float vv = acc[nf][r] + bv_[nf];
                if constexpr (OUT_BF16) {
                    outB[idx] = f2bf(vv);
                } else {
                    if constexpr (ADD_RES) vv += res[idx];
                    outF[idx] = vv;
                }
            }
        }
    }
}

// ---------------------------------------------------------------------------
// maxpool 3x3 s2 p1 on bf16 conv output -> fp32 trunk
// ---------------------------------------------------------------------------
template<int S, int CO>
__global__ __launch_bounds__(256) void k_pool_b(
    const u16* __restrict__ in, float* __restrict__ out)
{
    constexpr int PS = S / 2;
    const int idx = blockIdx.x * 256 + threadIdx.x;
    int c8 = idx % (CO / 8); int r = idx / (CO / 8);
    const int px = r % PS; r /= PS;
    const int py = r % PS; const int n = r / PS;
    if (n >= 2048) return;
    float m[8];
    #pragma unroll
    for (int j = 0; j < 8; j++) m[j] = -3e38f;
    #pragma unroll
    for (int dy = 0; dy < 3; dy++) {
        const int y = 2 * py - 1 + dy;
        if ((unsigned)y >= (unsigned)S) continue;
        #pragma unroll
        for (int dx = 0; dx < 3; dx++) {
            const int x = 2 * px - 1 + dx;
            if ((unsigned)x >= (unsigned)S) continue;
            u16x8 v = *(const u16x8*)&in[((n * S + y) * S + x) * CO + c8 * 8];
            #pragma unroll
            for (int j = 0; j < 8; j++) m[j] = fmaxf(m[j], bf2f(v[j]));
        }
    }
    float* op = &out[((n * PS + py) * PS + px) * CO + c8 * 8];
    f4 o0 = {m[0], m[1], m[2], m[3]};
    f4 o1 = {m[4], m[5], m[6], m[7]};
    *(f4*)&op[0] = o0;
    *(f4*)&op[4] = o1;
}

// ---------------------------------------------------------------------------
// GEMM: out[M,N] = op(A[M,K]) @ B[N,K]^T + bias. 64x64 tile, Kc=64.
// ---------------------------------------------------------------------------
template<bool GATHER_B, bool RELU_A, bool RELU_OUT, bool TWO_BIAS>
__global__ __launch_bounds__(256) void k_gemm(
    const float* __restrict__ A, const float* __restrict__ Bm,
    const float* __restrict__ b1, const float* __restrict__ b2,
    float* __restrict__ out, int M, int N, int K)
{
    __shared__ __align__(16) float aL[64*72];
    __shared__ __align__(16) float bL[64*72];
    const int tid = threadIdx.x;
    const int nb = N >> 6;
    const int m0 = (blockIdx.x / nb) << 6;
    const int n0 = (blockIdx.x % nb) << 6;
    const int mt = tid & 15, nt = tid >> 4;
    f4 acc[4] = {f4z(),f4z(),f4z(),f4z()};
    for (int kc = 0; kc < K; kc += 64) {
        __syncthreads();
        #pragma unroll
        for (int i = 0; i < 16; i++) {
            int flat = i*256 + tid;
            int kk = flat & 63, mm = flat >> 6;
            float av = A[(m0+mm)*K + kc+kk];
            if (RELU_A) av = fmaxf(av, 0.f);
            aL[kk*72 + mm] = av;
            int kg = kc + kk;
            float bv;
            if constexpr (GATHER_B)
                bv = Bm[(n0+mm)*K + (kg & 31)*64 + (kg >> 5)];
            else
                bv = Bm[(n0+mm)*K + kg];
            bL[kk*72 + mm] = bv;
        }
        __syncthreads();
        #pragma unroll
        for (int k = 0; k < 64; k++) {
            f4 a4 = *(const f4*)&aL[k*72 + mt*4];
            f4 b4 = *(const f4*)&bL[k*72 + nt*4];
            acc[0] += a4.x * b4;
            acc[1] += a4.y * b4;
            acc[2] += a4.z * b4;
            acc[3] += a4.w * b4;
        }
    }
    f4 bias = *(const f4*)&b1[n0 + nt*4];
    if constexpr (TWO_BIAS) bias += *(const f4*)&b2[n0 + nt*4];
    #pragma unroll
    for (int mi = 0; mi < 4; mi++) {
        f4 v = acc[mi] + bias;
        if (RELU_OUT) v = relu4(v);
        *(f4*)&out[(m0 + mt*4 + mi)*N + n0 + nt*4] = v;
    }
}

// ---------------------------------------------------------------------------
// persistent LSTM: 64 WGs. Barrier: release-add arrive; poll with RELAXED
// atomic fetch_add(0) — RMW always executes at the MALL coherence point, so
// it observes remote-XCD arrivals (a relaxed LOAD may not, and can hang);
// then ONE acquire RMW (DCE-proof) emits the single L2-invalidate per step.
// ---------------------------------------------------------------------------
__global__ __launch_bounds__(256) void k_lstm(
    const float* __restrict__ pre, const int* __restrict__ done,
    const float* __restrict__ h0, const float* __restrict__ c0,
    const float* __restrict__ whh,
    float* __restrict__ hbuf, unsigned* __restrict__ cnt,
    float* __restrict__ out)
{
    __shared__ __align__(16) float hLT[256*36];
    __shared__ __align__(16) float wLT[256*20];
    __shared__ __align__(16) float red[4096];
    __shared__ float gL[512];
    __shared__ float cL[128];
    __shared__ float mL[32];
    const int tid = threadIdx.x;
    const int j0 = blockIdx.x * 4;
    for (int e = tid; e < 4096; e += 256) {
        int r = e & 15, k = e >> 4;
        int rg = (r >> 2)*256 + j0 + (r & 3);
        wLT[k*20 + r] = whh[rg*256 + k];
    }
    if (tid < 128) cL[tid] = c0[(tid >> 2)*256 + j0 + (tid & 3)];
    const int bt = tid & 7, rt = (tid >> 3) & 3, ks = tid >> 5;
    for (int st = 0; st < 64; st++) {
        __syncthreads();
        if (tid < 32) mL[tid] = 1.f - (float)done[st*32 + tid];
        __syncthreads();
        const float* hsrc = (st == 0) ? h0 : (hbuf + (st & 1)*8192);
        for (int e = tid; e < 2048; e += 256) {
            int b = e & 31, k4 = e >> 5;
            float mm = mL[b];
            f4 v = *(const f4*)&hsrc[b*256 + k4*4];
            hLT[(k4*4+0)*36 + b] = v.x*mm;
            hLT[(k4*4+1)*36 + b] = v.y*mm;
            hLT[(k4*4+2)*36 + b] = v.z*mm;
            hLT[(k4*4+3)*36 + b] = v.w*mm;
        }
        if (tid < 128) cL[tid] *= mL[tid >> 2];
        __syncthreads();
        f4 acc[4] = {f4z(),f4z(),f4z(),f4z()};
        #pragma unroll
        for (int kk = 0; kk < 32; kk++) {
            int k = ks*32 + kk;
            f4 w4 = *(const f4*)&wLT[k*20 + rt*4];
            f4 h4 = *(const f4*)&hLT[k*36 + bt*4];
            acc[0] += w4.x * h4;
            acc[1] += w4.y * h4;
            acc[2] += w4.z * h4;
            acc[3] += w4.w * h4;
        }
        {
            f4* rp = (f4*)&red[((ks*32) + rt*8 + bt)*16];
            rp[0] = acc[0]; rp[1] = acc[1]; rp[2] = acc[2]; rp[3] = acc[3];
        }
        __syncthreads();
        #pragma unroll
        for (int o2 = 0; o2 < 2; o2++) {
            int o = tid*2 + o2;
            int r = o >> 5, b = o & 31;
            int tl = (r >> 2)*8 + (b >> 2);
            int e = (r & 3)*4 + (b & 3);
            float s = 0.f;
            #pragma unroll
            for (int q = 0; q < 8; q++) s += red[(q*32 + tl)*16 + e];
            s += pre[(st*32 + b)*1024 + (r >> 2)*256 + j0 + (r & 3)];
            gL[o] = s;
        }
        __syncthreads();
        if (tid < 128) {
            int b = tid >> 2, jl = tid & 3;
            float iv = gL[(jl     )*32 + b];
            float fv = gL[(4 + jl )*32 + b];
            float gv = gL[(8 + jl )*32 + b];
            float ov = gL[(12 + jl)*32 + b];
            float c = sigm(fv)*cL[tid] + sigm(iv)*tanhf(gv);
            cL[tid] = c;
            float h = sigm(ov)*tanhf(c);
            hbuf[((st+1) & 1)*8192 + b*256 + j0 + jl] = h;
            out[(st*32 + b)*256 + j0 + jl] = h;
        }
        __syncthreads();   // drains each wave's h stores (vmcnt0) before arrive
        if (st < 63) {
            if (tid == 0) {
                __hip_atomic_fetch_add(&cnt[st], 1u, __ATOMIC_RELEASE, __HIP_MEMORY_SCOPE_AGENT);
                while (__hip_atomic_fetch_add(&cnt[st], 0u, __ATOMIC_RELAXED, __HIP_MEMORY_SCOPE_AGENT) < 64u)
                    __builtin_amdgcn_s_sleep(2);
                __hip_atomic_fetch_add(&cnt[st], 0u, __ATOMIC_ACQUIRE, __HIP_MEMORY_SCOPE_AGENT);
            }
            __syncthreads();
        }
    }
}

// ---------------------------------------------------------------------------
extern "C" void kernel_launch(void* const* d_in, const int* in_sizes, int n_in,
                              void* d_out, int out_size, void* d_ws, size_t ws_size,
                              hipStream_t stream)
{
    (void)in_sizes; (void)n_in; (void)out_size; (void)ws_size;
    const float* x   = (const float*)d_in[0];
    const int*   dn  = (const int*)  d_in[1];
    const float* h0  = (const float*)d_in[2];
    const float* c0  = (const float*)d_in[3];
    const float* cw0 = (const float*)d_in[4];
    const float* cb0 = (const float*)d_in[5];
    const float* rw0 = (const float*)d_in[6];
    const float* rb0 = (const float*)d_in[7];
    const float* cw1 = (const float*)d_in[8];
    const float* cb1 = (const float*)d_in[9];
    const float* rw1 = (const float*)d_in[10];
    const float* rb1 = (const float*)d_in[11];
    const float* cw2 = (const float*)d_in[12];
    const float* cb2 = (const float*)d_in[13];
    const float* rw2 = (const float*)d_in[14];
    const float* rb2 = (const float*)d_in[15];
    const float* fcw = (const float*)d_in[16];
    const float* fcb = (const float*)d_in[17];
    const float* wih = (const float*)d_in[18];
    const float* whh = (const float*)d_in[19];
    const float* bih = (const float*)d_in[20];
    const float* bhh = (const float*)d_in[21];

    char* wsb = (char*)d_ws;
    float* P0 = (float*)wsb;                         // [2048,32,32,16] f32  128MiB
    float* T0 = (float*)(wsb + 134217728ull);
    u16*   C1 = (u16*)  (wsb + 134217728ull);        // [2048,32,32,32] bf16
    float* P1 = (float*)wsb;                         // [2048,16,16,32] f32
    float* T1 = (float*)(wsb + 67108864ull);
    u16*   C2 = (u16*)  (wsb + 134217728ull);        // [2048,16,16,32] bf16
    float* P2 = (float*)wsb;                         // [2048,8,8,32] f32
    float* T2 = (float*)(wsb + 16777216ull);
    float* hid  = (float*)(wsb + 33554432ull);       // [2048,256] f32
    float* preb = (float*)(wsb + 36700160ull);       // [2048,1024] f32
    float* hbuf = (float*)(wsb + 46137344ull);       // 2x[32,256] f32
    unsigned* cnt = (unsigned*)(wsb + 46268416ull);

    // seq0: conv0+pool (MFMA), 2 res blocks (C=16, img32, MFMA)
    k_conv0_mfma<<<dim3(8192), dim3(256), 0, stream>>>(x, cw0, cb0, P0);
    k_conv_mfma<16,16,32,16,32,1,true,false,false><<<dim3(4096), dim3(256), 0, stream>>>(P0, rw0,        rb0,    nullptr, T0, nullptr);
    k_conv_mfma<16,16,32,16,32,1,true,true ,false><<<dim3(4096), dim3(256), 0, stream>>>(T0, rw0+2304,   rb0+16, P0,      P0, nullptr);
    k_conv_mfma<16,16,32,16,32,1,true,false,false><<<dim3(4096), dim3(256), 0, stream>>>(P0, rw0+2*2304, rb0+32, nullptr, T0, nullptr);
    k_conv_mfma<16,16,32,16,32,1,true,true ,false><<<dim3(4096), dim3(256), 0, stream>>>(T0, rw0+3*2304, rb0+48, P0,      P0, nullptr);
    // seq1
    k_conv_mfma<16,32,32,16,32,1,false,false,true><<<dim3(4096), dim3(256), 0, stream>>>(P0, cw1, cb1, nullptr, nullptr, C1);
    k_pool_b<32,32><<<dim3(8192), dim3(256), 0, stream>>>(C1, P1);
    k_conv_mfma<32,32,16,16,16,1,true,false,false><<<dim3(2048), dim3(256), 0, stream>>>(P1, rw1,        rb1,    nullptr, T1, nullptr);
    k_conv_mfma<32,32,16,16,16,1,true,true ,false><<<dim3(2048), dim3(256), 0, stream>>>(T1, rw1+9216,   rb1+32, P1,      P1, nullptr);
    k_conv_mfma<32,32,16,16,16,1,true,false,false><<<dim3(2048), dim3(256), 0, stream>>>(P1, rw1+2*9216, rb1+64, nullptr, T1, nullptr);
    k_conv_mfma<32,32,16,16,16,1,true,true ,false><<<dim3(2048), dim3(256), 0, stream>>>(T1, rw1+3*9216, rb1+96, P1,      P1, nullptr);
    // seq2
    k_conv_mfma<32,32,16,16,16,1,false,false,true><<<dim3(2048), dim3(256), 0, stream>>>(P1, cw2, cb2, nullptr, nullptr, C2);
    k_pool_b<16,32><<<dim3(2048), dim3(256), 0, stream>>>(C2, P2);
    k_conv_mfma<32,32,8,8,8,4,true,false,false><<<dim3(512), dim3(256), 0, stream>>>(P2, rw2,        rb2,    nullptr, T2, nullptr);
    k_conv_mfma<32,32,8,8,8,4,true,true ,false><<<dim3(512), dim3(256), 0, stream>>>(T2, rw2+9216,   rb2+32, P2,      P2, nullptr);
    k_conv_mfma<32,32,8,8,8,4,true,false,false><<<dim3(512), dim3(256), 0, stream>>>(P2, rw2+2*9216, rb2+64, nullptr, T2, nullptr);
    k_conv_mfma<32,32,8,8,8,4,true,true ,false><<<dim3(512), dim3(256), 0, stream>>>(T2, rw2+3*9216, rb2+96, P2,      P2, nullptr);
    // FC + LSTM input projection + recurrent LSTM
    k_gemm<true,true,true,false><<<dim3(128), dim3(256), 0, stream>>>(P2, fcw, fcb, nullptr, hid, 2048, 256, 2048);
    k_gemm<false,false,false,true><<<dim3(512), dim3(256), 0, stream>>>(hid, wih, bih, bhh, preb, 2048, 1024, 256);
    hipMemsetAsync(cnt, 0, 256, stream);
    k_lstm<<<dim3(64), dim3(256), 0, stream>>>(preb, dn, h0, c0, whh, hbuf, cnt, (float*)d_out);
}

// Round 7
// 1501.819 us; speedup vs baseline: 2.4744x; 1.1782x over previous
//
#include <hip/hip_runtime.h>

typedef float f4 __attribute__((ext_vector_type(4)));
typedef short s8v __attribute__((ext_vector_type(8)));
typedef unsigned short u16;
typedef unsigned int u32;
typedef u16 u16x4 __attribute__((ext_vector_type(4)));
typedef u16 u16x8 __attribute__((ext_vector_type(8)));
typedef u32 u32x4 __attribute__((ext_vector_type(4)));

#define DI __device__ __forceinline__

DI f4 f4z() { f4 z = {0.f,0.f,0.f,0.f}; return z; }
DI f4 max4(f4 a, f4 b) {
    f4 r; r.x=fmaxf(a.x,b.x); r.y=fmaxf(a.y,b.y);
    r.z=fmaxf(a.z,b.z); r.w=fmaxf(a.w,b.w); return r;
}
DI f4 relu4(f4 a) { return max4(a, f4z()); }
DI float sigm(float x) { return 1.f/(1.f+expf(-x)); }

DI u16 f2bf(float x) {                      // RNE float->bf16
    unsigned u = __builtin_bit_cast(unsigned, x);
    u += 0x7FFFu + ((u >> 16) & 1u);
    return (u16)(u >> 16);
}
DI float bf2f(u16 b) {
    unsigned u = ((unsigned)b) << 16;
    return __builtin_bit_cast(float, u);
}
DI f4 mfma16(s8v a, s8v b, f4 c) {
    return __builtin_amdgcn_mfma_f32_16x16x32_bf16(a, b, c, 0, 0, 0);
}

// ---------------------------------------------------------------------------
// conv0 MFMA: (3->16, 3x3, pad1) + maxpool(3,s2,p1).  (validated round 4)
// ---------------------------------------------------------------------------
__global__ __launch_bounds__(256) void k_conv0_mfma(
    const float* __restrict__ x, const float* __restrict__ w,
    const float* __restrict__ bias, float* __restrict__ out)
{
    __shared__ __align__(16) u16 inS[36*36*4];
    __shared__ __align__(16) u16 wT[16*72];
    __shared__ __align__(16) u16 convL[33*34*16];
    const int tid = threadIdx.x;
    const int bid = blockIdx.x;
    const int n = bid >> 2, q = bid & 3;
    const int py0 = (q >> 1) * 16, px0 = (q & 1) * 16;
    const int iy0 = 2*py0 - 2, ix0 = 2*px0 - 2;

    for (int e = tid; e < 1024; e += 256) {
        const int k = e & 63, co = e >> 6;
        const int tap = k >> 2, ci = k & 3;
        u16 v = 0;
        if (tap < 9 && ci < 3) v = f2bf(w[(co*3 + ci)*9 + tap]);
        wT[co*72 + k] = v;
    }
    for (int e = tid; e < 1296; e += 256) {
        const int ix = e % 36, iy = e / 36;
        const int gy = iy0 + iy, gx = ix0 + ix;
        u16x4 pk = {0,0,0,0};
        if ((unsigned)gy < 64u && (unsigned)gx < 64u) {
            const float* xp = &x[((n*64 + gy)*64 + gx)*3];
            pk.x = f2bf(xp[0] * (1.f/255.f));
            pk.y = f2bf(xp[1] * (1.f/255.f));
            pk.z = f2bf(xp[2] * (1.f/255.f));
        }
        *(u16x4*)&inS[(iy*36 + ix)*4] = pk;
    }
    __syncthreads();

    const int lane = tid & 63, wv = tid >> 6;
    const int p = lane & 15, g = lane >> 4;
    const s8v B0 = *(const s8v*)&wT[p*72 + g*8];
    const s8v B1 = *(const s8v*)&wT[p*72 + 32 + g*8];
    const int t0 = 2*g, t1 = 2*g + 1;
    const int dy0 = t0/3, dx0 = t0%3, dy1 = t1/3, dx1 = t1%3;

    for (int t = wv; t < 99; t += 4) {
        const int y = t / 3, xb = (t % 3) * 16;
        const int xr = xb + p;
        const int ia = min(xr + dx0, 35), ib = min(xr + dx1, 35), ic = min(xr + 2, 35);
        u16x4 a0 = *(const u16x4*)&inS[((y + dy0)*36 + ia)*4];
        u16x4 a1 = *(const u16x4*)&inS[((y + dy1)*36 + ib)*4];
        u16x4 a2 = *(const u16x4*)&inS[((y + 2  )*36 + ic)*4];
        s8v A0, A1;
        A0[0]=a0.x; A0[1]=a0.y; A0[2]=a0.z; A0[3]=a0.w;
        A0[4]=a1.x; A0[5]=a1.y; A0[6]=a1.z; A0[7]=a1.w;
        A1[0]=a2.x; A1[1]=a2.y; A1[2]=a2.z; A1[3]=a2.w;
        A1[4]=a2.x; A1[5]=a2.y; A1[6]=a2.z; A1[7]=a2.w;
        f4 acc = mfma16(A0, B0, f4z());
        acc = mfma16(A1, B1, acc);
        #pragma unroll
        for (int r = 0; r < 4; r++) {
            const int xo = xb + g*4 + r;
            if (xo < 33) convL[(y*34 + xo)*16 + p] = f2bf(acc[r]);
        }
    }
    __syncthreads();
    for (int it = tid; it < 512; it += 256) {
        const int c8 = it & 1;
        const int pp = it >> 1;
        const int lpx = pp & 15, lpy = pp >> 4;
        float m[8];
        #pragma unroll
        for (int j = 0; j < 8; j++) m[j] = -3e38f;
        #pragma unroll
        for (int dy = 0; dy < 3; dy++) {
            const int ya = 2*(py0 + lpy) - 1 + dy;
            if ((unsigned)ya >= 64u) continue;
            const int yr = 2*lpy + dy;
            #pragma unroll
            for (int dx = 0; dx < 3; dx++) {
                const int xa = 2*(px0 + lpx) - 1 + dx;
                if ((unsigned)xa >= 64u) continue;
                const int xr = 2*lpx + dx;
                u16x8 v = *(const u16x8*)&convL[(yr*34 + xr)*16 + c8*8];
                #pragma unroll
                for (int j = 0; j < 8; j++) m[j] = fmaxf(m[j], bf2f(v[j]));
            }
        }
        f4 o0 = {m[0]+bias[c8*8+0], m[1]+bias[c8*8+1], m[2]+bias[c8*8+2], m[3]+bias[c8*8+3]};
        f4 o1 = {m[4]+bias[c8*8+4], m[5]+bias[c8*8+5], m[6]+bias[c8*8+6], m[7]+bias[c8*8+7]};
        float* op = &out[((n*32 + py0+lpy)*32 + px0+lpx)*16 + c8*8];
        *(f4*)&op[0] = o0;
        *(f4*)&op[4] = o1;
    }
}

// ---------------------------------------------------------------------------
// bf16-MFMA conv3x3 pad1, NHWC (validated round 2)
// ---------------------------------------------------------------------------
template<int CIN, int COUT, int IMG, int TH, int TW, int NPB,
         bool RELU_IN, bool ADD_RES, bool OUT_BF16>
__global__ __launch_bounds__(256) void k_conv_mfma(
    const float* __restrict__ in, const float* __restrict__ w,
    const float* __restrict__ bias, const float* __restrict__ res,
    float* __restrict__ outF, u16* __restrict__ outB)
{
    constexpr int CP  = CIN + 8;
    constexpr int IH  = TH + 2, WL = TW + 2;
    constexpr int KM  = (CIN == 16) ? 5 : 9;
    constexpr int KLD = KM * 32;
    constexpr int KPW = KLD + 8;
    constexpr int NF  = COUT / 16;
    constexpr int FR  = TH / 4, FC = TW / 4;
    constexpr int NFRAG = NPB * FR * FC;
    constexpr int TY = IMG / TH, TX = IMG / TW, TILES = TY * TX;

    __shared__ __align__(16) u16 inL[NPB * IH * WL * CP];
    __shared__ __align__(16) u16 wT[COUT * KPW];

    const int tid = threadIdx.x;
    const int bid = blockIdx.x;
    const int n0 = (bid / TILES) * NPB;
    const int tt = bid % TILES;
    const int y0 = (tt / TX) * TH;
    const int x0 = (tt % TX) * TW;

    for (int e = tid; e < COUT * KLD; e += 256) {
        int k = e % KLD, co = e / KLD;
        u16 bv = 0;
        if (k < 9 * CIN) {
            int tap = k / CIN, ci = k % CIN;
            bv = f2bf(w[(co * CIN + ci) * 9 + tap]);
        }
        wT[co * KPW + k] = bv;
    }
    constexpr int SIT = NPB * IH * WL * (CIN / 4);
    for (int e = tid; e < SIT; e += 256) {
        int c4 = e % (CIN / 4); int r = e / (CIN / 4);
        int ix = r % WL; r /= WL;
        int iy = r % IH; int nl = r / IH;
        int gy = y0 - 1 + iy, gx = x0 - 1 + ix;
        f4 v = f4z();
        if ((unsigned)gy < (unsigned)IMG && (unsigned)gx < (unsigned)IMG) {
            v = *(const f4*)&in[(((n0 + nl) * IMG + gy) * IMG + gx) * CIN + c4 * 4];
            if (RELU_IN) v = relu4(v);
        }
        u16x4 b;
        b.x = f2bf(v.x); b.y = f2bf(v.y); b.z = f2bf(v.z); b.w = f2bf(v.w);
        *(u16x4*)&inL[((nl * IH + iy) * WL + ix) * CP + c4 * 4] = b;
    }
    __syncthreads();

    const int lane = tid & 63, wv = tid >> 6;
    const int p = lane & 15, g = lane >> 4;
    const int pr = p >> 2, pc = p & 3;

    int ci0;
    int aoff[KM];
    if constexpr (CIN == 32) {
        ci0 = g * 8;
        #pragma unroll
        for (int kk = 0; kk < KM; kk++)
            aoff[kk] = ((kk / 3) * WL + (kk % 3)) * CP;
    } else {
        ci0 = (g & 1) * 8;
        const int gh = g >> 1;
        #pragma unroll
        for (int kk = 0; kk < KM; kk++) {
            int t = 2 * kk + gh;
            if (t > 8) t = 8;
            aoff[kk] = ((t / 3) * WL + (t % 3)) * CP;
        }
    }
    s8v Bf[KM][NF];
    #pragma unroll
    for (int kk = 0; kk < KM; kk++)
        #pragma unroll
        for (int nf = 0; nf < NF; nf++)
            Bf[kk][nf] = *(const s8v*)&wT[(nf * 16 + p) * KPW + kk * 32 + g * 8];

    float bv_[NF];
    #pragma unroll
    for (int nf = 0; nf < NF; nf++) bv_[nf] = bias[nf * 16 + p];

    for (int f = wv; f < NFRAG; f += 4) {
        const int nl = f / (FR * FC);
        const int rem = f % (FR * FC);
        const int fr = rem / FC, fc = rem % FC;
        const int abase = ((nl * IH + fr * 4 + pr) * WL + fc * 4 + pc) * CP + ci0;
        f4 acc[NF];
        #pragma unroll
        for (int nf = 0; nf < NF; nf++) acc[nf] = f4z();
        #pragma unroll
        for (int kk = 0; kk < KM; kk++) {
            s8v a = *(const s8v*)&inL[abase + aoff[kk]];
            #pragma unroll
            for (int nf = 0; nf < NF; nf++)
                acc[nf] = mfma16(a, Bf[kk][nf], acc[nf]);
        }
        const int n = n0 + nl;
        const int gy = y0 + fr * 4 + g;
        #pragma unroll
        for (int nf = 0; nf < NF; nf++) {
            const int co = nf * 16 + p;
            #pragma unroll
            for (int r = 0; r < 4; r++) {
                const int gx = x0 + fc * 4 + r;
                const int idx = ((n * IMG + gy) * IMG + gx) * COUT + co;
                float vv = acc[nf][r] + bv_[nf];
                if constexpr (OUT_BF16) {
                    outB[idx] = f2bf(vv);
                } else {
                    if constexpr (ADD_RES) vv += res[idx];
                    outF[idx] = vv;
                }
            }
        }
    }
}

// ---------------------------------------------------------------------------
// maxpool 3x3 s2 p1 on bf16 conv output -> fp32 trunk
// ---------------------------------------------------------------------------
template<int S, int CO>
__global__ __launch_bounds__(256) void k_pool_b(
    const u16* __restrict__ in, float* __restrict__ out)
{
    constexpr int PS = S / 2;
    const int idx = blockIdx.x * 256 + threadIdx.x;
    int c8 = idx % (CO / 8); int r = idx / (CO / 8);
    const int px = r % PS; r /= PS;
    const int py = r % PS; const int n = r / PS;
    if (n >= 2048) return;
    float m[8];
    #pragma unroll
    for (int j = 0; j < 8; j++) m[j] = -3e38f;
    #pragma unroll
    for (int dy = 0; dy < 3; dy++) {
        const int y = 2 * py - 1 + dy;
        if ((unsigned)y >= (unsigned)S) continue;
        #pragma unroll
        for (int dx = 0; dx < 3; dx++) {
            const int x = 2 * px - 1 + dx;
            if ((unsigned)x >= (unsigned)S) continue;
            u16x8 v = *(const u16x8*)&in[((n * S + y) * S + x) * CO + c8 * 8];
            #pragma unroll
            for (int j = 0; j < 8; j++) m[j] = fmaxf(m[j], bf2f(v[j]));
        }
    }
    float* op = &out[((n * PS + py) * PS + px) * CO + c8 * 8];
    f4 o0 = {m[0], m[1], m[2], m[3]};
    f4 o1 = {m[4], m[5], m[6], m[7]};
    *(f4*)&op[0] = o0;
    *(f4*)&op[4] = o1;
}

// ---------------------------------------------------------------------------
// GEMM: out[M,N] = op(A[M,K]) @ B[N,K]^T + bias. 64x64 tile, Kc=64.
// ---------------------------------------------------------------------------
template<bool GATHER_B, bool RELU_A, bool RELU_OUT, bool TWO_BIAS>
__global__ __launch_bounds__(256) void k_gemm(
    const float* __restrict__ A, const float* __restrict__ Bm,
    const float* __restrict__ b1, const float* __restrict__ b2,
    float* __restrict__ out, int M, int N, int K)
{
    __shared__ __align__(16) float aL[64*72];
    __shared__ __align__(16) float bL[64*72];
    const int tid = threadIdx.x;
    const int nb = N >> 6;
    const int m0 = (blockIdx.x / nb) << 6;
    const int n0 = (blockIdx.x % nb) << 6;
    const int mt = tid & 15, nt = tid >> 4;
    f4 acc[4] = {f4z(),f4z(),f4z(),f4z()};
    for (int kc = 0; kc < K; kc += 64) {
        __syncthreads();
        #pragma unroll
        for (int i = 0; i < 16; i++) {
            int flat = i*256 + tid;
            int kk = flat & 63, mm = flat >> 6;
            float av = A[(m0+mm)*K + kc+kk];
            if (RELU_A) av = fmaxf(av, 0.f);
            aL[kk*72 + mm] = av;
            int kg = kc + kk;
            float bv;
            if constexpr (GATHER_B)
                bv = Bm[(n0+mm)*K + (kg & 31)*64 + (kg >> 5)];
            else
                bv = Bm[(n0+mm)*K + kg];
            bL[kk*72 + mm] = bv;
        }
        __syncthreads();
        #pragma unroll
        for (int k = 0; k < 64; k++) {
            f4 a4 = *(const f4*)&aL[k*72 + mt*4];
            f4 b4 = *(const f4*)&bL[k*72 + nt*4];
            acc[0] += a4.x * b4;
            acc[1] += a4.y * b4;
            acc[2] += a4.z * b4;
            acc[3] += a4.w * b4;
        }
    }
    f4 bias = *(const f4*)&b1[n0 + nt*4];
    if constexpr (TWO_BIAS) bias += *(const f4*)&b2[n0 + nt*4];
    #pragma unroll
    for (int mi = 0; mi < 4; mi++) {
        f4 v = acc[mi] + bias;
        if (RELU_OUT) v = relu4(v);
        *(f4*)&out[(m0 + mt*4 + mi)*N + n0 + nt*4] = v;
    }
}

// ---------------------------------------------------------------------------
// k_lstm16: 16 WGs x 256 thr. WG owns 16 hidden units (all 4 gates); wave =
// gate. w_hh stationary in registers as hi/lo-split bf16 B-frags. h exchanged
// as (hi,lo)-packed u32 via relaxed agent-scope atomics (served at MALL, no
// wbl2/inv fences). Barrier: relaxed RMW arrive + relaxed RMW poll.
// FIX r6: staging now covers the FULL k=0..255 range (32 elems/thread, was 16
// -> upper half of hBhi/hBlo was uninitialized LDS -> NaN).
// ---------------------------------------------------------------------------
__global__ __launch_bounds__(256) void k_lstm16(
    const float* __restrict__ pre, const int* __restrict__ done,
    const float* __restrict__ h0, const float* __restrict__ c0,
    const float* __restrict__ whh,
    u32* __restrict__ hx, unsigned* __restrict__ cnt,
    float* __restrict__ out)
{
    __shared__ __align__(16) u16 hBhi[32*264];   // h hi bf16, A-layout [b][k]
    __shared__ __align__(16) u16 hBlo[32*264];   // h lo bf16
    __shared__ float gL[4*32*17];                // gates [g][b][jl pad17]
    __shared__ float cL[512];                    // c [b][jl]
    __shared__ float mL[32];
    const int tid = threadIdx.x;
    const int wg  = blockIdx.x;
    const int j0  = wg * 16;
    const int lane = tid & 63, w = tid >> 6;     // w = gate
    const int p = lane & 15, g4 = lane >> 4;

    // ---- stage w_hh rows (gate w, units j0+p) -> hi/lo bf16 B-frags ----
    s8v Bhi[8], Blo[8];
    {
        const float* wr = &whh[(w*256 + j0 + p) * 256];
        #pragma unroll
        for (int kk = 0; kk < 8; kk++) {
            const float* wp = &wr[kk*32 + g4*8];
            f4 w0 = *(const f4*)&wp[0];
            f4 w1 = *(const f4*)&wp[4];
            s8v bh, bl;
            #pragma unroll
            for (int e = 0; e < 4; e++) {
                u16 h0_ = f2bf(w0[e]); u16 l0_ = f2bf(w0[e] - bf2f(h0_));
                u16 h1_ = f2bf(w1[e]); u16 l1_ = f2bf(w1[e] - bf2f(h1_));
                bh[e] = (short)h0_; bh[e+4] = (short)h1_;
                bl[e] = (short)l0_; bl[e+4] = (short)l1_;
            }
            Bhi[kk] = bh; Blo[kk] = bl;
        }
    }
    // ---- c init: 512 vals / 256 thr ----
    #pragma unroll
    for (int q = 0; q < 2; q++) {
        int idx = q*256 + tid;
        int b = idx >> 4, jl = idx & 15;
        cL[idx] = c0[b*256 + j0 + jl];
    }

    const int sb = tid >> 3, ss = tid & 7;       // stage map: (batch, 32-elem k-grp)
    for (int st = 0; st < 64; st++) {
        if (tid < 32) mL[tid] = (done[st*32 + tid] != 0) ? 0.f : 1.f;
        __syncthreads();
        // ---- stage h (masked, hi/lo split) into LDS: 32 elems/thread ----
        if (st == 0) {
            const float mm = mL[sb];
            const float* hp = &h0[sb*256 + ss*32];
            #pragma unroll
            for (int i = 0; i < 32; i++) {
                float v = hp[i] * mm;
                u16 hi = f2bf(v);
                u16 lo = f2bf(v - bf2f(hi));
                hBhi[sb*264 + ss*32 + i] = hi;
                hBlo[sb*264 + ss*32 + i] = lo;
            }
        } else {
            const bool live = (mL[sb] != 0.f);
            const u32* src = &hx[(st & 1)*8192 + sb*256];
            u32 rh[16], rl[16];
            #pragma unroll
            for (int i = 0; i < 16; i++)
                rh[i] = live ? __hip_atomic_load(&src[ss*16 + i], __ATOMIC_RELAXED, __HIP_MEMORY_SCOPE_AGENT) : 0u;
            #pragma unroll
            for (int i = 0; i < 16; i++)
                rl[i] = live ? __hip_atomic_load(&src[128 + ss*16 + i], __ATOMIC_RELAXED, __HIP_MEMORY_SCOPE_AGENT) : 0u;
            #pragma unroll
            for (int qq = 0; qq < 4; qq++) {
                u32x4 a = {rh[qq*4], rh[qq*4+1], rh[qq*4+2], rh[qq*4+3]};
                u32x4 b = {rl[qq*4], rl[qq*4+1], rl[qq*4+2], rl[qq*4+3]};
                *(u32x4*)&hBhi[sb*264 + ss*32 + qq*8] = a;
                *(u32x4*)&hBlo[sb*264 + ss*32 + qq*8] = b;
            }
        }
        __syncthreads();
        // ---- recurrent GEMM: gate w, units j0..j0+15, all 32 batch ----
        f4 acc0 = f4z(), acc1 = f4z();
        #pragma unroll
        for (int kk = 0; kk < 8; kk++) {
            const int o0 = (0*16 + p)*264 + kk*32 + g4*8;
            const int o1 = (1*16 + p)*264 + kk*32 + g4*8;
            s8v ah0 = *(const s8v*)&hBhi[o0];
            s8v al0 = *(const s8v*)&hBlo[o0];
            s8v ah1 = *(const s8v*)&hBhi[o1];
            s8v al1 = *(const s8v*)&hBlo[o1];
            acc0 = mfma16(ah0, Bhi[kk], acc0);
            acc0 = mfma16(al0, Bhi[kk], acc0);
            acc0 = mfma16(ah0, Blo[kk], acc0);
            acc1 = mfma16(ah1, Bhi[kk], acc1);
            acc1 = mfma16(al1, Bhi[kk], acc1);
            acc1 = mfma16(ah1, Blo[kk], acc1);
        }
        // ---- add pre, write gates to LDS ----
        #pragma unroll
        for (int r = 0; r < 4; r++) {
            const int b0_ = g4*4 + r, b1_ = 16 + g4*4 + r;
            gL[(w*32 + b0_)*17 + p] = acc0[r] + pre[(st*32 + b0_)*1024 + w*256 + j0 + p];
            gL[(w*32 + b1_)*17 + p] = acc1[r] + pre[(st*32 + b1_)*1024 + w*256 + j0 + p];
        }
        __syncthreads();
        // ---- cell update: thread = (b, unit pair) ----
        {
            const int b = tid >> 3, jl2 = tid & 7;
            const float mm = mL[b];
            float hv[2];
            #pragma unroll
            for (int q = 0; q < 2; q++) {
                const int jl = jl2*2 + q;
                const float iv = gL[(0*32 + b)*17 + jl];
                const float fv = gL[(1*32 + b)*17 + jl];
                const float gv = gL[(2*32 + b)*17 + jl];
                const float ov = gL[(3*32 + b)*17 + jl];
                const float cold = cL[b*16 + jl] * mm;
                const float c = sigm(fv)*cold + sigm(iv)*tanhf(gv);
                cL[b*16 + jl] = c;
                const float h = sigm(ov)*tanhf(c);
                out[(st*32 + b)*256 + j0 + jl] = h;
                hv[q] = h;
            }
            u16 h0b = f2bf(hv[0]);
            u16 h1b = f2bf(hv[1]);
            u32 hp = ((u32)h1b << 16) | (u32)h0b;
            u32 lp = ((u32)f2bf(hv[1] - bf2f(h1b)) << 16) | (u32)f2bf(hv[0] - bf2f(h0b));
            u32* dst = &hx[((st+1) & 1)*8192 + b*256];
            __hip_atomic_store(&dst[wg*8 + jl2], hp, __ATOMIC_RELAXED, __HIP_MEMORY_SCOPE_AGENT);
            __hip_atomic_store(&dst[128 + wg*8 + jl2], lp, __ATOMIC_RELAXED, __HIP_MEMORY_SCOPE_AGENT);
        }
        __syncthreads();   // drains h stores (vmcnt 0) before arrive
        if (st < 63) {
            if (tid == 0) {
                __hip_atomic_fetch_add(&cnt[st], 1u, __ATOMIC_RELAXED, __HIP_MEMORY_SCOPE_AGENT);
                while (__hip_atomic_fetch_add(&cnt[st], 0u, __ATOMIC_RELAXED, __HIP_MEMORY_SCOPE_AGENT) < 16u)
                    __builtin_amdgcn_s_sleep(1);
            }
            __syncthreads();
        }
    }
}

// ---------------------------------------------------------------------------
extern "C" void kernel_launch(void* const* d_in, const int* in_sizes, int n_in,
                              void* d_out, int out_size, void* d_ws, size_t ws_size,
                              hipStream_t stream)
{
    (void)in_sizes; (void)n_in; (void)out_size; (void)ws_size;
    const float* x   = (const float*)d_in[0];
    const int*   dn  = (const int*)  d_in[1];
    const float* h0  = (const float*)d_in[2];
    const float* c0  = (const float*)d_in[3];
    const float* cw0 = (const float*)d_in[4];
    const float* cb0 = (const float*)d_in[5];
    const float* rw0 = (const float*)d_in[6];
    const float* rb0 = (const float*)d_in[7];
    const float* cw1 = (const float*)d_in[8];
    const float* cb1 = (const float*)d_in[9];
    const float* rw1 = (const float*)d_in[10];
    const float* rb1 = (const float*)d_in[11];
    const float* cw2 = (const float*)d_in[12];
    const float* cb2 = (const float*)d_in[13];
    const float* rw2 = (const float*)d_in[14];
    const float* rb2 = (const float*)d_in[15];
    const float* fcw = (const float*)d_in[16];
    const float* fcb = (const float*)d_in[17];
    const float* wih = (const float*)d_in[18];
    const float* whh = (const float*)d_in[19];
    const float* bih = (const float*)d_in[20];
    const float* bhh = (const float*)d_in[21];

    char* wsb = (char*)d_ws;
    float* P0 = (float*)wsb;                         // [2048,32,32,16] f32  128MiB
    float* T0 = (float*)(wsb + 134217728ull);
    u16*   C1 = (u16*)  (wsb + 134217728ull);        // [2048,32,32,32] bf16
    float* P1 = (float*)wsb;                         // [2048,16,16,32] f32
    float* T1 = (float*)(wsb + 67108864ull);
    u16*   C2 = (u16*)  (wsb + 134217728ull);        // [2048,16,16,32] bf16
    float* P2 = (float*)wsb;                         // [2048,8,8,32] f32
    float* T2 = (float*)(wsb + 16777216ull);
    float* hid  = (float*)(wsb + 33554432ull);       // [2048,256] f32
    float* preb = (float*)(wsb + 36700160ull);       // [2048,1024] f32
    u32*   hx   = (u32*)  (wsb + 46137344ull);       // 2x[32,256] u32 (hi|lo bf16)
    unsigned* cnt = (unsigned*)(wsb + 46268416ull);

    // seq0: conv0+pool (MFMA), 2 res blocks (C=16, img32, MFMA)
    k_conv0_mfma<<<dim3(8192), dim3(256), 0, stream>>>(x, cw0, cb0, P0);
    k_conv_mfma<16,16,32,16,32,1,true,false,false><<<dim3(4096), dim3(256), 0, stream>>>(P0, rw0,        rb0,    nullptr, T0, nullptr);
    k_conv_mfma<16,16,32,16,32,1,true,true ,false><<<dim3(4096), dim3(256), 0, stream>>>(T0, rw0+2304,   rb0+16, P0,      P0, nullptr);
    k_conv_mfma<16,16,32,16,32,1,true,false,false><<<dim3(4096), dim3(256), 0, stream>>>(P0, rw0+2*2304, rb0+32, nullptr, T0, nullptr);
    k_conv_mfma<16,16,32,16,32,1,true,true ,false><<<dim3(4096), dim3(256), 0, stream>>>(T0, rw0+3*2304, rb0+48, P0,      P0, nullptr);
    // seq1
    k_conv_mfma<16,32,32,16,32,1,false,false,true><<<dim3(4096), dim3(256), 0, stream>>>(P0, cw1, cb1, nullptr, nullptr, C1);
    k_pool_b<32,32><<<dim3(8192), dim3(256), 0, stream>>>(C1, P1);
    k_conv_mfma<32,32,16,16,16,1,true,false,false><<<dim3(2048), dim3(256), 0, stream>>>(P1, rw1,        rb1,    nullptr, T1, nullptr);
    k_conv_mfma<32,32,16,16,16,1,true,true ,false><<<dim3(2048), dim3(256), 0, stream>>>(T1, rw1+9216,   rb1+32, P1,      P1, nullptr);
    k_conv_mfma<32,32,16,16,16,1,true,false,false><<<dim3(2048), dim3(256), 0, stream>>>(P1, rw1+2*9216, rb1+64, nullptr, T1, nullptr);
    k_conv_mfma<32,32,16,16,16,1,true,true ,false><<<dim3(2048), dim3(256), 0, stream>>>(T1, rw1+3*9216, rb1+96, P1,      P1, nullptr);
    // seq2
    k_conv_mfma<32,32,16,16,16,1,false,false,true><<<dim3(2048), dim3(256), 0, stream>>>(P1, cw2, cb2, nullptr, nullptr, C2);
    k_pool_b<16,32><<<dim3(2048), dim3(256), 0, stream>>>(C2, P2);
    k_conv_mfma<32,32,8,8,8,4,true,false,false><<<dim3(512), dim3(256), 0, stream>>>(P2, rw2,        rb2,    nullptr, T2, nullptr);
    k_conv_mfma<32,32,8,8,8,4,true,true ,false><<<dim3(512), dim3(256), 0, stream>>>(T2, rw2+9216,   rb2+32, P2,      P2, nullptr);
    k_conv_mfma<32,32,8,8,8,4,true,false,false><<<dim3(512), dim3(256), 0, stream>>>(P2, rw2+2*9216, rb2+64, nullptr, T2, nullptr);
    k_conv_mfma<32,32,8,8,8,4,true,true ,false><<<dim3(512), dim3(256), 0, stream>>>(T2, rw2+3*9216, rb2+96, P2,      P2, nullptr);
    // FC + LSTM input projection + recurrent LSTM
    k_gemm<true,true,true,false><<<dim3(128), dim3(256), 0, stream>>>(P2, fcw, fcb, nullptr, hid, 2048, 256, 2048);
    k_gemm<false,false,false,true><<<dim3(512), dim3(256), 0, stream>>>(hid, wih, bih, bhh, preb, 2048, 1024, 256);
    hipMemsetAsync(cnt, 0, 256, stream);
    k_lstm16<<<dim3(16), dim3(256), 0, stream>>>(preb, dn, h0, c0, whh, hx, cnt, (float*)d_out);
}

// Round 8
// 1216.212 us; speedup vs baseline: 3.0555x; 1.2348x over previous
//
#include <hip/hip_runtime.h>

typedef float f4 __attribute__((ext_vector_type(4)));
typedef short s8v __attribute__((ext_vector_type(8)));
typedef unsigned short u16;
typedef unsigned int u32;
typedef unsigned long long u64;
typedef u16 u16x4 __attribute__((ext_vector_type(4)));
typedef u16 u16x8 __attribute__((ext_vector_type(8)));
typedef u32 u32x4 __attribute__((ext_vector_type(4)));

#define DI __device__ __forceinline__

DI f4 f4z() { f4 z = {0.f,0.f,0.f,0.f}; return z; }
DI float sigm(float x) { return 1.f/(1.f+expf(-x)); }

DI u16 f2bf(float x) {                      // RNE float->bf16
    unsigned u = __builtin_bit_cast(unsigned, x);
    u += 0x7FFFu + ((u >> 16) & 1u);
    return (u16)(u >> 16);
}
DI float bf2f(u16 b) {
    unsigned u = ((unsigned)b) << 16;
    return __builtin_bit_cast(float, u);
}
DI f4 mfma16(s8v a, s8v b, f4 c) {
    return __builtin_amdgcn_mfma_f32_16x16x32_bf16(a, b, c, 0, 0, 0);
}
DI u32 lo32(u64 v) { return (u32)v; }
DI u32 hi32(u64 v) { return (u32)(v >> 32); }

// ---------------------------------------------------------------------------
// conv0 MFMA: (3->16, 3x3, pad1) + maxpool(3,s2,p1) -> bf16 trunk.
// ---------------------------------------------------------------------------
__global__ __launch_bounds__(256) void k_conv0_mfma(
    const float* __restrict__ x, const float* __restrict__ w,
    const float* __restrict__ bias, u16* __restrict__ out)
{
    __shared__ __align__(16) u16 inS[36*36*4];
    __shared__ __align__(16) u16 wT[16*72];
    __shared__ __align__(16) u16 convL[33*34*16];
    const int tid = threadIdx.x;
    const int bid = blockIdx.x;
    const int n = bid >> 2, q = bid & 3;
    const int py0 = (q >> 1) * 16, px0 = (q & 1) * 16;
    const int iy0 = 2*py0 - 2, ix0 = 2*px0 - 2;

    for (int e = tid; e < 1024; e += 256) {
        const int k = e & 63, co = e >> 6;
        const int tap = k >> 2, ci = k & 3;
        u16 v = 0;
        if (tap < 9 && ci < 3) v = f2bf(w[(co*3 + ci)*9 + tap]);
        wT[co*72 + k] = v;
    }
    for (int e = tid; e < 1296; e += 256) {
        const int ix = e % 36, iy = e / 36;
        const int gy = iy0 + iy, gx = ix0 + ix;
        u16x4 pk = {0,0,0,0};
        if ((unsigned)gy < 64u && (unsigned)gx < 64u) {
            const float* xp = &x[((n*64 + gy)*64 + gx)*3];
            pk.x = f2bf(xp[0] * (1.f/255.f));
            pk.y = f2bf(xp[1] * (1.f/255.f));
            pk.z = f2bf(xp[2] * (1.f/255.f));
        }
        *(u16x4*)&inS[(iy*36 + ix)*4] = pk;
    }
    __syncthreads();

    const int lane = tid & 63, wv = tid >> 6;
    const int p = lane & 15, g = lane >> 4;
    const s8v B0 = *(const s8v*)&wT[p*72 + g*8];
    const s8v B1 = *(const s8v*)&wT[p*72 + 32 + g*8];
    const int t0 = 2*g, t1 = 2*g + 1;
    const int dy0 = t0/3, dx0 = t0%3, dy1 = t1/3, dx1 = t1%3;

    for (int t = wv; t < 99; t += 4) {
        const int y = t / 3, xb = (t % 3) * 16;
        const int xr = xb + p;
        const int ia = min(xr + dx0, 35), ib = min(xr + dx1, 35), ic = min(xr + 2, 35);
        u16x4 a0 = *(const u16x4*)&inS[((y + dy0)*36 + ia)*4];
        u16x4 a1 = *(const u16x4*)&inS[((y + dy1)*36 + ib)*4];
        u16x4 a2 = *(const u16x4*)&inS[((y + 2  )*36 + ic)*4];
        s8v A0, A1;
        A0[0]=a0.x; A0[1]=a0.y; A0[2]=a0.z; A0[3]=a0.w;
        A0[4]=a1.x; A0[5]=a1.y; A0[6]=a1.z; A0[7]=a1.w;
        A1[0]=a2.x; A1[1]=a2.y; A1[2]=a2.z; A1[3]=a2.w;
        A1[4]=a2.x; A1[5]=a2.y; A1[6]=a2.z; A1[7]=a2.w;
        f4 acc = mfma16(A0, B0, f4z());
        acc = mfma16(A1, B1, acc);
        #pragma unroll
        for (int r = 0; r < 4; r++) {
            const int xo = xb + g*4 + r;
            if (xo < 33) convL[(y*34 + xo)*16 + p] = f2bf(acc[r]);
        }
    }
    __syncthreads();
    for (int it = tid; it < 512; it += 256) {
        const int c8 = it & 1;
        const int pp = it >> 1;
        const int lpx = pp & 15, lpy = pp >> 4;
        float m[8];
        #pragma unroll
        for (int j = 0; j < 8; j++) m[j] = -3e38f;
        #pragma unroll
        for (int dy = 0; dy < 3; dy++) {
            const int ya = 2*(py0 + lpy) - 1 + dy;
            if ((unsigned)ya >= 64u) continue;
            const int yr = 2*lpy + dy;
            #pragma unroll
            for (int dx = 0; dx < 3; dx++) {
                const int xa = 2*(px0 + lpx) - 1 + dx;
                if ((unsigned)xa >= 64u) continue;
                const int xr = 2*lpx + dx;
                u16x8 v = *(const u16x8*)&convL[(yr*34 + xr)*16 + c8*8];
                #pragma unroll
                for (int j = 0; j < 8; j++) m[j] = fmaxf(m[j], bf2f(v[j]));
            }
        }
        u16x8 o;
        #pragma unroll
        for (int j = 0; j < 8; j++) o[j] = f2bf(m[j] + bias[c8*8 + j]);
        *(u16x8*)&out[((n*32 + py0+lpy)*32 + px0+lpx)*16 + c8*8] = o;
    }
}

// ---------------------------------------------------------------------------
// bf16-MFMA conv3x3 pad1, NHWC, bf16 in/out trunk. Layout validated round 2.
// ---------------------------------------------------------------------------
template<int CIN, int COUT, int IMG, int TH, int TW, int NPB,
         bool RELU_IN, bool ADD_RES>
__global__ __launch_bounds__(256) void k_conv_bf(
    const u16* __restrict__ in, const float* __restrict__ w,
    const float* __restrict__ bias, const u16* __restrict__ res,
    u16* __restrict__ out)
{
    constexpr int CP  = CIN + 8;
    constexpr int IH  = TH + 2, WL = TW + 2;
    constexpr int KM  = (CIN == 16) ? 5 : 9;
    constexpr int KLD = KM * 32;
    constexpr int KPW = KLD + 8;
    constexpr int NF  = COUT / 16;
    constexpr int FR  = TH / 4, FC = TW / 4;
    constexpr int NFRAG = NPB * FR * FC;
    constexpr int TY = IMG / TH, TX = IMG / TW, TILES = TY * TX;

    __shared__ __align__(16) u16 inL[NPB * IH * WL * CP];
    __shared__ __align__(16) u16 wT[COUT * KPW];

    const int tid = threadIdx.x;
    const int bid = blockIdx.x;
    const int n0 = (bid / TILES) * NPB;
    const int tt = bid % TILES;
    const int y0 = (tt / TX) * TH;
    const int x0 = (tt % TX) * TW;

    for (int e = tid; e < COUT * KLD; e += 256) {
        int k = e % KLD, co = e / KLD;
        u16 bv = 0;
        if (k < 9 * CIN) {
            int tap = k / CIN, ci = k % CIN;
            bv = f2bf(w[(co * CIN + ci) * 9 + tap]);
        }
        wT[co * KPW + k] = bv;
    }
    constexpr int SIT = NPB * IH * WL * (CIN / 8);
    for (int e = tid; e < SIT; e += 256) {
        int c8 = e % (CIN / 8); int r = e / (CIN / 8);
        int ix = r % WL; r /= WL;
        int iy = r % IH; int nl = r / IH;
        int gy = y0 - 1 + iy, gx = x0 - 1 + ix;
        u16x8 v = {0,0,0,0,0,0,0,0};
        if ((unsigned)gy < (unsigned)IMG && (unsigned)gx < (unsigned)IMG) {
            v = *(const u16x8*)&in[(((n0 + nl) * IMG + gy) * IMG + gx) * CIN + c8 * 8];
            if (RELU_IN) {
                #pragma unroll
                for (int j = 0; j < 8; j++) v[j] = (v[j] & 0x8000u) ? (u16)0 : v[j];
            }
        }
        *(u16x8*)&inL[((nl * IH + iy) * WL + ix) * CP + c8 * 8] = v;
    }
    __syncthreads();

    const int lane = tid & 63, wv = tid >> 6;
    const int p = lane & 15, g = lane >> 4;
    const int pr = p >> 2, pc = p & 3;

    int ci0;
    int aoff[KM];
    if constexpr (CIN == 32) {
        ci0 = g * 8;
        #pragma unroll
        for (int kk = 0; kk < KM; kk++)
            aoff[kk] = ((kk / 3) * WL + (kk % 3)) * CP;
    } else {
        ci0 = (g & 1) * 8;
        const int gh = g >> 1;
        #pragma unroll
        for (int kk = 0; kk < KM; kk++) {
            int t = 2 * kk + gh;
            if (t > 8) t = 8;
            aoff[kk] = ((t / 3) * WL + (t % 3)) * CP;
        }
    }
    s8v Bf[KM][NF];
    #pragma unroll
    for (int kk = 0; kk < KM; kk++)
        #pragma unroll
        for (int nf = 0; nf < NF; nf++)
            Bf[kk][nf] = *(const s8v*)&wT[(nf * 16 + p) * KPW + kk * 32 + g * 8];

    float bv_[NF];
    #pragma unroll
    for (int nf = 0; nf < NF; nf++) bv_[nf] = bias[nf * 16 + p];

    for (int f = wv; f < NFRAG; f += 4) {
        const int nl = f / (FR * FC);
        const int rem = f % (FR * FC);
        const int fr = rem / FC, fc = rem % FC;
        const int abase = ((nl * IH + fr * 4 + pr) * WL + fc * 4 + pc) * CP + ci0;
        f4 acc[NF];
        #pragma unroll
        for (int nf = 0; nf < NF; nf++) acc[nf] = f4z();
        #pragma unroll
        for (int kk = 0; kk < KM; kk++) {
            s8v a = *(const s8v*)&inL[abase + aoff[kk]];
            #pragma unroll
            for (int nf = 0; nf < NF; nf++)
                acc[nf] = mfma16(a, Bf[kk][nf], acc[nf]);
        }
        const int n = n0 + nl;
        const int gy = y0 + fr * 4 + g;
        #pragma unroll
        for (int nf = 0; nf < NF; nf++) {
            const int co = nf * 16 + p;
            #pragma unroll
            for (int r = 0; r < 4; r++) {
                const int gx = x0 + fc * 4 + r;
                const int idx = ((n * IMG + gy) * IMG + gx) * COUT + co;
                float vv = acc[nf][r] + bv_[nf];
                if constexpr (ADD_RES) vv += bf2f(res[idx]);
                out[idx] = f2bf(vv);
            }
        }
    }
}

// ---------------------------------------------------------------------------
// maxpool 3x3 s2 p1, bf16 -> bf16 (max of bf16 is exact; bias pre-added)
// ---------------------------------------------------------------------------
template<int S, int CO>
__global__ __launch_bounds__(256) void k_pool_b(
    const u16* __restrict__ in, u16* __restrict__ out)
{
    constexpr int PS = S / 2;
    const int idx = blockIdx.x * 256 + threadIdx.x;
    int c8 = idx % (CO / 8); int r = idx / (CO / 8);
    const int px = r % PS; r /= PS;
    const int py = r % PS; const int n = r / PS;
    if (n >= 2048) return;
    float m[8];
    #pragma unroll
    for (int j = 0; j < 8; j++) m[j] = -3e38f;
    #pragma unroll
    for (int dy = 0; dy < 3; dy++) {
        const int y = 2 * py - 1 + dy;
        if ((unsigned)y >= (unsigned)S) continue;
        #pragma unroll
        for (int dx = 0; dx < 3; dx++) {
            const int x = 2 * px - 1 + dx;
            if ((unsigned)x >= (unsigned)S) continue;
            u16x8 v = *(const u16x8*)&in[((n * S + y) * S + x) * CO + c8 * 8];
            #pragma unroll
            for (int j = 0; j < 8; j++) m[j] = fmaxf(m[j], bf2f(v[j]));
        }
    }
    u16x8 o;
    #pragma unroll
    for (int j = 0; j < 8; j++) o[j] = f2bf(m[j]);
    *(u16x8*)&out[((n * PS + py) * PS + px) * CO + c8 * 8] = o;
}

// ---------------------------------------------------------------------------
// GEMM: out[M,N] = op(A[M,K]) @ B[N,K]^T + bias. 64x64 tile, Kc=64.
// ABF16: A is bf16 (the trunk); else f32.
// ---------------------------------------------------------------------------
template<bool GATHER_B, bool RELU_A, bool RELU_OUT, bool TWO_BIAS, bool ABF16>
__global__ __launch_bounds__(256) void k_gemm(
    const void* __restrict__ Av, const float* __restrict__ Bm,
    const float* __restrict__ b1, const float* __restrict__ b2,
    float* __restrict__ out, int M, int N, int K)
{
    __shared__ __align__(16) float aL[64*72];
    __shared__ __align__(16) float bL[64*72];
    const int tid = threadIdx.x;
    const int nb = N >> 6;
    const int m0 = (blockIdx.x / nb) << 6;
    const int n0 = (blockIdx.x % nb) << 6;
    const int mt = tid & 15, nt = tid >> 4;
    f4 acc[4] = {f4z(),f4z(),f4z(),f4z()};
    for (int kc = 0; kc < K; kc += 64) {
        __syncthreads();
        #pragma unroll
        for (int i = 0; i < 16; i++) {
            int flat = i*256 + tid;
            int kk = flat & 63, mm = flat >> 6;
            float av;
            if constexpr (ABF16)
                av = bf2f(((const u16*)Av)[(m0+mm)*K + kc+kk]);
            else
                av = ((const float*)Av)[(m0+mm)*K + kc+kk];
            if (RELU_A) av = fmaxf(av, 0.f);
            aL[kk*72 + mm] = av;
            int kg = kc + kk;
            float bv;
            if constexpr (GATHER_B)
                bv = Bm[(n0+mm)*K + (kg & 31)*64 + (kg >> 5)];
            else
                bv = Bm[(n0+mm)*K + kg];
            bL[kk*72 + mm] = bv;
        }
        __syncthreads();
        #pragma unroll
        for (int k = 0; k < 64; k++) {
            f4 a4 = *(const f4*)&aL[k*72 + mt*4];
            f4 b4 = *(const f4*)&bL[k*72 + nt*4];
            acc[0] += a4.x * b4;
            acc[1] += a4.y * b4;
            acc[2] += a4.z * b4;
            acc[3] += a4.w * b4;
        }
    }
    f4 bias = *(const f4*)&b1[n0 + nt*4];
    if constexpr (TWO_BIAS) bias += *(const f4*)&b2[n0 + nt*4];
    #pragma unroll
    for (int mi = 0; mi < 4; mi++) {
        f4 v = acc[mi] + bias;
        if (RELU_OUT) {
            v.x=fmaxf(v.x,0.f); v.y=fmaxf(v.y,0.f);
            v.z=fmaxf(v.z,0.f); v.w=fmaxf(v.w,0.f);
        }
        *(f4*)&out[(m0 + mt*4 + mi)*N + n0 + nt*4] = v;
    }
}

// ---------------------------------------------------------------------------
// k_lstm16 v2: 16 WGs x 256 thr. As round 7 (validated), plus:
//  - u64 relaxed atomic loads for h staging (16/thread, was 32 u32)
//  - pre prefetched into regs at step top (overlaps staging latency)
//  - done-mask per-thread scalar (staging batch == cell batch) - one sync less
//  - c state in registers (thread-private across steps)
// ---------------------------------------------------------------------------
__global__ __launch_bounds__(256) void k_lstm16(
    const float* __restrict__ pre, const int* __restrict__ done,
    const float* __restrict__ h0, const float* __restrict__ c0,
    const float* __restrict__ whh,
    u32* __restrict__ hx, unsigned* __restrict__ cnt,
    float* __restrict__ out)
{
    __shared__ __align__(16) u16 hBhi[32*264];   // h hi bf16, [b][k]
    __shared__ __align__(16) u16 hBlo[32*264];   // h lo bf16
    __shared__ float gL[4*32*17];                // gates [g][b][jl pad17]
    const int tid = threadIdx.x;
    const int wg  = blockIdx.x;
    const int j0  = wg * 16;
    const int lane = tid & 63, w = tid >> 6;     // w = gate
    const int p = lane & 15, g4 = lane >> 4;

    // ---- stage w_hh rows (gate w, units j0+p) -> hi/lo bf16 B-frags ----
    s8v Bhi[8], Blo[8];
    {
        const float* wr = &whh[(w*256 + j0 + p) * 256];
        #pragma unroll
        for (int kk = 0; kk < 8; kk++) {
            const float* wp = &wr[kk*32 + g4*8];
            f4 w0 = *(const f4*)&wp[0];
            f4 w1 = *(const f4*)&wp[4];
            s8v bh, bl;
            #pragma unroll
            for (int e = 0; e < 4; e++) {
                u16 h0_ = f2bf(w0[e]); u16 l0_ = f2bf(w0[e] - bf2f(h0_));
                u16 h1_ = f2bf(w1[e]); u16 l1_ = f2bf(w1[e] - bf2f(h1_));
                bh[e] = (short)h0_; bh[e+4] = (short)h1_;
                bl[e] = (short)l0_; bl[e+4] = (short)l1_;
            }
            Bhi[kk] = bh; Blo[kk] = bl;
        }
    }
    const int sb = tid >> 3, ss = tid & 7;       // staging/cell batch + k-group
    const int jl2 = tid & 7;                     // cell unit-pair
    float cr0 = c0[sb*256 + j0 + jl2*2];
    float cr1 = c0[sb*256 + j0 + jl2*2 + 1];

    for (int st = 0; st < 64; st++) {
        const float mm = (done[st*32 + sb] != 0) ? 0.f : 1.f;
        // ---- prefetch pre (independent of h) ----
        float preR[8];
        #pragma unroll
        for (int r = 0; r < 4; r++) {
            preR[r]   = pre[(st*32 + g4*4 + r)*1024 + w*256 + j0 + p];
            preR[4+r] = pre[(st*32 + 16 + g4*4 + r)*1024 + w*256 + j0 + p];
        }
        // ---- stage h (masked, hi/lo) into LDS: 32 bf16/thread ----
        if (st == 0) {
            const float* hp = &h0[sb*256 + ss*32];
            #pragma unroll
            for (int i = 0; i < 32; i++) {
                float v = hp[i] * mm;
                u16 hi = f2bf(v);
                u16 lo = f2bf(v - bf2f(hi));
                hBhi[sb*264 + ss*32 + i] = hi;
                hBlo[sb*264 + ss*32 + i] = lo;
            }
        } else {
            const u64* src = (const u64*)&hx[(st & 1)*8192 + sb*256];
            u64 rh[8], rl[8];
            if (mm != 0.f) {
                #pragma unroll
                for (int i = 0; i < 8; i++)
                    rh[i] = __hip_atomic_load(&src[ss*8 + i], __ATOMIC_RELAXED, __HIP_MEMORY_SCOPE_AGENT);
                #pragma unroll
                for (int i = 0; i < 8; i++)
                    rl[i] = __hip_atomic_load(&src[64 + ss*8 + i], __ATOMIC_RELAXED, __HIP_MEMORY_SCOPE_AGENT);
            } else {
                #pragma unroll
                for (int i = 0; i < 8; i++) { rh[i] = 0; rl[i] = 0; }
            }
            #pragma unroll
            for (int qq = 0; qq < 4; qq++) {
                u32x4 a = {lo32(rh[qq*2]), hi32(rh[qq*2]), lo32(rh[qq*2+1]), hi32(rh[qq*2+1])};
                u32x4 b = {lo32(rl[qq*2]), hi32(rl[qq*2]), lo32(rl[qq*2+1]), hi32(rl[qq*2+1])};
                *(u32x4*)&hBhi[sb*264 + ss*32 + qq*8] = a;
                *(u32x4*)&hBlo[sb*264 + ss*32 + qq*8] = b;
            }
        }
        __syncthreads();
        // ---- recurrent GEMM (gate w, units j0..j0+15, 32 batch) ----
        f4 acc0 = f4z(), acc1 = f4z();
        #pragma unroll
        for (int kk = 0; kk < 8; kk++) {
            const int o0 = p*264 + kk*32 + g4*8;
            const int o1 = (16 + p)*264 + kk*32 + g4*8;
            s8v ah0 = *(const s8v*)&hBhi[o0];
            s8v al0 = *(const s8v*)&hBlo[o0];
            s8v ah1 = *(const s8v*)&hBhi[o1];
            s8v al1 = *(const s8v*)&hBlo[o1];
            acc0 = mfma16(ah0, Bhi[kk], acc0);
            acc0 = mfma16(al0, Bhi[kk], acc0);
            acc0 = mfma16(ah0, Blo[kk], acc0);
            acc1 = mfma16(ah1, Bhi[kk], acc1);
            acc1 = mfma16(al1, Bhi[kk], acc1);
            acc1 = mfma16(ah1, Blo[kk], acc1);
        }
        #pragma unroll
        for (int r = 0; r < 4; r++) {
            gL[(w*32 + g4*4 + r)*17 + p]      = acc0[r] + preR[r];
            gL[(w*32 + 16 + g4*4 + r)*17 + p] = acc1[r] + preR[4+r];
        }
        __syncthreads();
        // ---- cell update: thread = (batch sb, unit pair jl2) ----
        {
            float hv[2];
            float cr[2] = {cr0, cr1};
            #pragma unroll
            for (int q = 0; q < 2; q++) {
                const int jl = jl2*2 + q;
                const float iv = gL[(0*32 + sb)*17 + jl];
                const float fv = gL[(1*32 + sb)*17 + jl];
                const float gv = gL[(2*32 + sb)*17 + jl];
                const float ov = gL[(3*32 + sb)*17 + jl];
                const float c = sigm(fv)*(cr[q]*mm) + sigm(iv)*tanhf(gv);
                cr[q] = c;
                const float h = sigm(ov)*tanhf(c);
                out[(st*32 + sb)*256 + j0 + jl] = h;
                hv[q] = h;
            }
            cr0 = cr[0]; cr1 = cr[1];
            u16 h0b = f2bf(hv[0]);
            u16 h1b = f2bf(hv[1]);
            u32 hp = ((u32)h1b << 16) | (u32)h0b;
            u32 lp = ((u32)f2bf(hv[1] - bf2f(h1b)) << 16) | (u32)f2bf(hv[0] - bf2f(h0b));
            u32* dst = &hx[((st+1) & 1)*8192 + sb*256];
            __hip_atomic_store(&dst[wg*8 + jl2], hp, __ATOMIC_RELAXED, __HIP_MEMORY_SCOPE_AGENT);
            __hip_atomic_store(&dst[128 + wg*8 + jl2], lp, __ATOMIC_RELAXED, __HIP_MEMORY_SCOPE_AGENT);
        }
        __syncthreads();   // drains h stores (vmcnt 0) before arrive
        if (st < 63) {
            if (tid == 0) {
                __hip_atomic_fetch_add(&cnt[st], 1u, __ATOMIC_RELAXED, __HIP_MEMORY_SCOPE_AGENT);
                while (__hip_atomic_fetch_add(&cnt[st], 0u, __ATOMIC_RELAXED, __HIP_MEMORY_SCOPE_AGENT) < 16u)
                    __builtin_amdgcn_s_sleep(1);
            }
            __syncthreads();
        }
    }
}

// ---------------------------------------------------------------------------
extern "C" void kernel_launch(void* const* d_in, const int* in_sizes, int n_in,
                              void* d_out, int out_size, void* d_ws, size_t ws_size,
                              hipStream_t stream)
{
    (void)in_sizes; (void)n_in; (void)out_size; (void)ws_size;
    const float* x   = (const float*)d_in[0];
    const int*   dn  = (const int*)  d_in[1];
    const float* h0  = (const float*)d_in[2];
    const float* c0  = (const float*)d_in[3];
    const float* cw0 = (const float*)d_in[4];
    const float* cb0 = (const float*)d_in[5];
    const float* rw0 = (const float*)d_in[6];
    const float* rb0 = (const float*)d_in[7];
    const float* cw1 = (const float*)d_in[8];
    const float* cb1 = (const float*)d_in[9];
    const float* rw1 = (const float*)d_in[10];
    const float* rb1 = (const float*)d_in[11];
    const float* cw2 = (const float*)d_in[12];
    const float* cb2 = (const float*)d_in[13];
    const float* rw2 = (const float*)d_in[14];
    const float* rb2 = (const float*)d_in[15];
    const float* fcw = (const float*)d_in[16];
    const float* fcb = (const float*)d_in[17];
    const float* wih = (const float*)d_in[18];
    const float* whh = (const float*)d_in[19];
    const float* bih = (const float*)d_in[20];
    const float* bhh = (const float*)d_in[21];

    char* wsb = (char*)d_ws;
    // bf16 trunk buffers (lifetime-checked):
    u16* P0 = (u16*)wsb;                           // [2048,32,32,16] 64MB
    u16* T0 = (u16*)(wsb + 67108864ull);           // 64MB (ends 128MB)
    u16* C1 = (u16*)(wsb + 134217728ull);          // [2048,32,32,32] 128MB (ends 262MB)
    u16* P1 = (u16*)wsb;                           // [2048,16,16,32] 32MB
    u16* T1 = (u16*)(wsb + 33554432ull);           // 32MB
    u16* C2 = (u16*)(wsb + 134217728ull);          // [2048,16,16,32] 32MB (C1 dead)
    u16* P2 = (u16*)wsb;                           // [2048,8,8,32] 8MB
    u16* T2 = (u16*)(wsb + 8388608ull);            // 8MB
    float* hid  = (float*)(wsb + 67108864ull);     // [2048,256] f32 2MB (T0 dead)
    float* preb = (float*)(wsb + 71303168ull);     // [2048,1024] f32 8MB
    u32*   hx   = (u32*)  (wsb + 83886080ull);     // 2x[32,256] u32 (hi|lo)
    unsigned* cnt = (unsigned*)(wsb + 83951616ull);

    // seq0
    k_conv0_mfma<<<dim3(8192), dim3(256), 0, stream>>>(x, cw0, cb0, P0);
    k_conv_bf<16,16,32,16,32,1,true,false><<<dim3(4096), dim3(256), 0, stream>>>(P0, rw0,        rb0,    nullptr, T0);
    k_conv_bf<16,16,32,16,32,1,true,true ><<<dim3(4096), dim3(256), 0, stream>>>(T0, rw0+2304,   rb0+16, P0,      P0);
    k_conv_bf<16,16,32,16,32,1,true,false><<<dim3(4096), dim3(256), 0, stream>>>(P0, rw0+2*2304, rb0+32, nullptr, T0);
    k_conv_bf<16,16,32,16,32,1,true,true ><<<dim3(4096), dim3(256), 0, stream>>>(T0, rw0+3*2304, rb0+48, P0,      P0);
    // seq1
    k_conv_bf<16,32,32,16,32,1,false,false><<<dim3(4096), dim3(256), 0, stream>>>(P0, cw1, cb1, nullptr, C1);
    k_pool_b<32,32><<<dim3(8192), dim3(256), 0, stream>>>(C1, P1);
    k_conv_bf<32,32,16,16,16,1,true,false><<<dim3(2048), dim3(256), 0, stream>>>(P1, rw1,        rb1,    nullptr, T1);
    k_conv_bf<32,32,16,16,16,1,true,true ><<<dim3(2048), dim3(256), 0, stream>>>(T1, rw1+9216,   rb1+32, P1,      P1);
    k_conv_bf<32,32,16,16,16,1,true,false><<<dim3(2048), dim3(256), 0, stream>>>(P1, rw1+2*9216, rb1+64, nullptr, T1);
    k_conv_bf<32,32,16,16,16,1,true,true ><<<dim3(2048), dim3(256), 0, stream>>>(T1, rw1+3*9216, rb1+96, P1,      P1);
    // seq2
    k_conv_bf<32,32,16,16,16,1,false,false><<<dim3(2048), dim3(256), 0, stream>>>(P1, cw2, cb2, nullptr, C2);
    k_pool_b<16,32><<<dim3(2048), dim3(256), 0, stream>>>(C2, P2);
    k_conv_bf<32,32,8,8,8,4,true,false><<<dim3(512), dim3(256), 0, stream>>>(P2, rw2,        rb2,    nullptr, T2);
    k_conv_bf<32,32,8,8,8,4,true,true ><<<dim3(512), dim3(256), 0, stream>>>(T2, rw2+9216,   rb2+32, P2,      P2);
    k_conv_bf<32,32,8,8,8,4,true,false><<<dim3(512), dim3(256), 0, stream>>>(P2, rw2+2*9216, rb2+64, nullptr, T2);
    k_conv_bf<32,32,8,8,8,4,true,true ><<<dim3(512), dim3(256), 0, stream>>>(T2, rw2+3*9216, rb2+96, P2,      P2);
    // FC (bf16 A) + LSTM input projection (f32 A) + recurrent LSTM
    k_gemm<true,true,true,false,true ><<<dim3(128), dim3(256), 0, stream>>>(P2,  fcw, fcb, nullptr, hid,  2048, 256, 2048);
    k_gemm<false,false,false,true,false><<<dim3(512), dim3(256), 0, stream>>>(hid, wih, bih, bhh,   preb, 2048, 1024, 256);
    hipMemsetAsync(cnt, 0, 256, stream);
    k_lstm16<<<dim3(16), dim3(256), 0, stream>>>(preb, dn, h0, c0, whh, hx, cnt, (float*)d_out);
}

// Round 9
// 1076.347 us; speedup vs baseline: 3.4526x; 1.1299x over previous
//
#include <hip/hip_runtime.h>

typedef float f4 __attribute__((ext_vector_type(4)));
typedef short s8v __attribute__((ext_vector_type(8)));
typedef unsigned short u16;
typedef unsigned int u32;
typedef unsigned long long u64;
typedef u16 u16x4 __attribute__((ext_vector_type(4)));
typedef u16 u16x8 __attribute__((ext_vector_type(8)));
typedef u32 u32x4 __attribute__((ext_vector_type(4)));

#define DI __device__ __forceinline__

DI f4 f4z() { f4 z = {0.f,0.f,0.f,0.f}; return z; }
DI float sigm(float x) { return 1.f/(1.f+expf(-x)); }

DI u16 f2bf(float x) {                      // RNE float->bf16
    unsigned u = __builtin_bit_cast(unsigned, x);
    u += 0x7FFFu + ((u >> 16) & 1u);
    return (u16)(u >> 16);
}
DI float bf2f(u16 b) {
    unsigned u = ((unsigned)b) << 16;
    return __builtin_bit_cast(float, u);
}
DI f4 mfma16(s8v a, s8v b, f4 c) {
    return __builtin_amdgcn_mfma_f32_16x16x32_bf16(a, b, c, 0, 0, 0);
}
DI u32 lo32(u64 v) { return (u32)v; }
DI u32 hi32(u64 v) { return (u32)(v >> 32); }

// wbuf offsets (u16 units): conv0 wT | rw0 x4 | cw1 | rw1 x4 | cw2 | rw2 x4
#define WB_C0   0
#define WB_RW0  1152       // + i*2688  (16 co x 168)
#define WB_CW1  11904      // 32 co x 168
#define WB_RW1  17280      // + i*9472  (32 co x 296)
#define WB_CW2  55168
#define WB_RW2  64640      // + i*9472
#define WB_TOT  102528

// ---------------------------------------------------------------------------
// weight prep: all conv weights -> bf16 in per-lane fragment layout [co][k].
// k = tap*CIN + ci (tap-major); conv0: k = tap*4 + ci, K=64.
// ---------------------------------------------------------------------------
__global__ __launch_bounds__(256) void k_prep(
    const float* __restrict__ cw0, const float* __restrict__ rw0,
    const float* __restrict__ cw1, const float* __restrict__ rw1,
    const float* __restrict__ cw2, const float* __restrict__ rw2,
    u16* __restrict__ wb)
{
    int e = blockIdx.x * 256 + threadIdx.x;
    if (e < 1024) {                              // conv0: 16co x 64k
        int co = e >> 6, k = e & 63, tap = k >> 2, ci = k & 3;
        u16 v = 0;
        if (tap < 9 && ci < 3) v = f2bf(cw0[(co*3 + ci)*9 + tap]);
        wb[WB_C0 + co*72 + k] = v;
        return;
    }
    e -= 1024;
    if (e < 10240) {                             // rw0: 4 x (16co x 160k)
        int i = e / 2560, l = e % 2560;
        int co = l / 160, k = l % 160;
        u16 v = (k < 144) ? f2bf(rw0[i*2304 + (co*16 + k%16)*9 + k/16]) : (u16)0;
        wb[WB_RW0 + i*2688 + co*168 + k] = v;
        return;
    }
    e -= 10240;
    if (e < 5120) {                              // cw1: 32co x 160k
        int co = e / 160, k = e % 160;
        u16 v = (k < 144) ? f2bf(cw1[(co*16 + k%16)*9 + k/16]) : (u16)0;
        wb[WB_CW1 + co*168 + k] = v;
        return;
    }
    e -= 5120;
    if (e < 36864) {                             // rw1: 4 x (32co x 288k)
        int i = e / 9216, l = e % 9216;
        int co = l / 288, k = l % 288;
        wb[WB_RW1 + i*9472 + co*296 + k] = f2bf(rw1[i*9216 + (co*32 + k%32)*9 + k/32]);
        return;
    }
    e -= 36864;
    if (e < 9216) {                              // cw2
        int co = e / 288, k = e % 288;
        wb[WB_CW2 + co*296 + k] = f2bf(cw2[(co*32 + k%32)*9 + k/32]);
        return;
    }
    e -= 9216;
    if (e < 36864) {                             // rw2
        int i = e / 9216, l = e % 9216;
        int co = l / 288, k = l % 288;
        wb[WB_RW2 + i*9472 + co*296 + k] = f2bf(rw2[i*9216 + (co*32 + k%32)*9 + k/32]);
    }
}

// ---------------------------------------------------------------------------
// conv0 MFMA: (3->16, 3x3, pad1) + maxpool(3,s2,p1) -> bf16 trunk.
// Weights prefetched from wbuf (no per-block staging).
// ---------------------------------------------------------------------------
__global__ __launch_bounds__(256) void k_conv0_mfma(
    const float* __restrict__ x, const u16* __restrict__ wg,
    const float* __restrict__ bias, u16* __restrict__ out)
{
    __shared__ __align__(16) u16 inS[36*36*4];
    __shared__ __align__(16) u16 convL[33*34*16];
    const int tid = threadIdx.x;
    const int bid = blockIdx.x;
    const int n = bid >> 2, q = bid & 3;
    const int py0 = (q >> 1) * 16, px0 = (q & 1) * 16;
    const int iy0 = 2*py0 - 2, ix0 = 2*px0 - 2;

    const int lane = tid & 63, wv = tid >> 6;
    const int p = lane & 15, g = lane >> 4;
    const s8v B0 = *(const s8v*)&wg[p*72 + g*8];
    const s8v B1 = *(const s8v*)&wg[p*72 + 32 + g*8];

    for (int e = tid; e < 1296; e += 256) {
        const int ix = e % 36, iy = e / 36;
        const int gy = iy0 + iy, gx = ix0 + ix;
        u16x4 pk = {0,0,0,0};
        if ((unsigned)gy < 64u && (unsigned)gx < 64u) {
            const float* xp = &x[((n*64 + gy)*64 + gx)*3];
            pk.x = f2bf(xp[0] * (1.f/255.f));
            pk.y = f2bf(xp[1] * (1.f/255.f));
            pk.z = f2bf(xp[2] * (1.f/255.f));
        }
        *(u16x4*)&inS[(iy*36 + ix)*4] = pk;
    }
    __syncthreads();

    const int t0 = 2*g, t1 = 2*g + 1;
    const int dy0 = t0/3, dx0 = t0%3, dy1 = t1/3, dx1 = t1%3;

    for (int t = wv; t < 99; t += 4) {
        const int y = t / 3, xb = (t % 3) * 16;
        const int xr = xb + p;
        const int ia = min(xr + dx0, 35), ib = min(xr + dx1, 35), ic = min(xr + 2, 35);
        u16x4 a0 = *(const u16x4*)&inS[((y + dy0)*36 + ia)*4];
        u16x4 a1 = *(const u16x4*)&inS[((y + dy1)*36 + ib)*4];
        u16x4 a2 = *(const u16x4*)&inS[((y + 2  )*36 + ic)*4];
        s8v A0, A1;
        A0[0]=a0.x; A0[1]=a0.y; A0[2]=a0.z; A0[3]=a0.w;
        A0[4]=a1.x; A0[5]=a1.y; A0[6]=a1.z; A0[7]=a1.w;
        A1[0]=a2.x; A1[1]=a2.y; A1[2]=a2.z; A1[3]=a2.w;
        A1[4]=a2.x; A1[5]=a2.y; A1[6]=a2.z; A1[7]=a2.w;
        f4 acc = mfma16(A0, B0, f4z());
        acc = mfma16(A1, B1, acc);
        #pragma unroll
        for (int r = 0; r < 4; r++) {
            const int xo = xb + g*4 + r;
            if (xo < 33) convL[(y*34 + xo)*16 + p] = f2bf(acc[r]);
        }
    }
    __syncthreads();
    for (int it = tid; it < 512; it += 256) {
        const int c8 = it & 1;
        const int pp = it >> 1;
        const int lpx = pp & 15, lpy = pp >> 4;
        float m[8];
        #pragma unroll
        for (int j = 0; j < 8; j++) m[j] = -3e38f;
        #pragma unroll
        for (int dy = 0; dy < 3; dy++) {
            const int ya = 2*(py0 + lpy) - 1 + dy;
            if ((unsigned)ya >= 64u) continue;
            const int yr = 2*lpy + dy;
            #pragma unroll
            for (int dx = 0; dx < 3; dx++) {
                const int xa = 2*(px0 + lpx) - 1 + dx;
                if ((unsigned)xa >= 64u) continue;
                const int xr = 2*lpx + dx;
                u16x8 v = *(const u16x8*)&convL[(yr*34 + xr)*16 + c8*8];
                #pragma unroll
                for (int j = 0; j < 8; j++) m[j] = fmaxf(m[j], bf2f(v[j]));
            }
        }
        u16x8 o;
        #pragma unroll
        for (int j = 0; j < 8; j++) o[j] = f2bf(m[j] + bias[c8*8 + j]);
        *(u16x8*)&out[((n*32 + py0+lpy)*32 + px0+lpx)*16 + c8*8] = o;
    }
}

// ---------------------------------------------------------------------------
// bf16-MFMA conv3x3 pad1, NHWC, bf16 trunk. B-frags loaded from wbuf (global,
// L2-broadcast) — no weight LDS, no per-block conversion.
// ---------------------------------------------------------------------------
template<int CIN, int COUT, int IMG, int TH, int TW, int NPB,
         bool RELU_IN, bool ADD_RES>
__global__ __launch_bounds__(256) void k_conv_bf(
    const u16* __restrict__ in, const u16* __restrict__ wg,
    const float* __restrict__ bias, const u16* __restrict__ res,
    u16* __restrict__ out)
{
    constexpr int CP  = CIN + 8;
    constexpr int IH  = TH + 2, WL = TW + 2;
    constexpr int KM  = (CIN == 16) ? 5 : 9;
    constexpr int KLD = KM * 32;
    constexpr int KPW = KLD + 8;
    constexpr int NF  = COUT / 16;
    constexpr int FR  = TH / 4, FC = TW / 4;
    constexpr int NFRAG = NPB * FR * FC;
    constexpr int TY = IMG / TH, TX = IMG / TW, TILES = TY * TX;

    __shared__ __align__(16) u16 inL[NPB * IH * WL * CP];

    const int tid = threadIdx.x;
    const int bid = blockIdx.x;
    const int n0 = (bid / TILES) * NPB;
    const int tt = bid % TILES;
    const int y0 = (tt / TX) * TH;
    const int x0 = (tt % TX) * TW;

    const int lane = tid & 63, wv = tid >> 6;
    const int p = lane & 15, g = lane >> 4;
    const int pr = p >> 2, pc = p & 3;

    // B-frags direct from global (same addresses across blocks -> L2 hit)
    s8v Bf[KM][NF];
    #pragma unroll
    for (int kk = 0; kk < KM; kk++)
        #pragma unroll
        for (int nf = 0; nf < NF; nf++)
            Bf[kk][nf] = *(const s8v*)&wg[(nf * 16 + p) * KPW + kk * 32 + g * 8];

    constexpr int SIT = NPB * IH * WL * (CIN / 8);
    for (int e = tid; e < SIT; e += 256) {
        int c8 = e % (CIN / 8); int r = e / (CIN / 8);
        int ix = r % WL; r /= WL;
        int iy = r % IH; int nl = r / IH;
        int gy = y0 - 1 + iy, gx = x0 - 1 + ix;
        u16x8 v = {0,0,0,0,0,0,0,0};
        if ((unsigned)gy < (unsigned)IMG && (unsigned)gx < (unsigned)IMG) {
            v = *(const u16x8*)&in[(((n0 + nl) * IMG + gy) * IMG + gx) * CIN + c8 * 8];
            if (RELU_IN) {
                #pragma unroll
                for (int j = 0; j < 8; j++) v[j] = (v[j] & 0x8000u) ? (u16)0 : v[j];
            }
        }
        *(u16x8*)&inL[((nl * IH + iy) * WL + ix) * CP + c8 * 8] = v;
    }
    __syncthreads();

    int ci0;
    int aoff[KM];
    if constexpr (CIN == 32) {
        ci0 = g * 8;
        #pragma unroll
        for (int kk = 0; kk < KM; kk++)
            aoff[kk] = ((kk / 3) * WL + (kk % 3)) * CP;
    } else {
        ci0 = (g & 1) * 8;
        const int gh = g >> 1;
        #pragma unroll
        for (int kk = 0; kk < KM; kk++) {
            int t = 2 * kk + gh;
            if (t > 8) t = 8;
            aoff[kk] = ((t / 3) * WL + (t % 3)) * CP;
        }
    }

    float bv_[NF];
    #pragma unroll
    for (int nf = 0; nf < NF; nf++) bv_[nf] = bias[nf * 16 + p];

    for (int f = wv; f < NFRAG; f += 4) {
        const int nl = f / (FR * FC);
        const int rem = f % (FR * FC);
        const int fr = rem / FC, fc = rem % FC;
        const int abase = ((nl * IH + fr * 4 + pr) * WL + fc * 4 + pc) * CP + ci0;
        f4 acc[NF];
        #pragma unroll
        for (int nf = 0; nf < NF; nf++) acc[nf] = f4z();
        #pragma unroll
        for (int kk = 0; kk < KM; kk++) {
            s8v a = *(const s8v*)&inL[abase + aoff[kk]];
            #pragma unroll
            for (int nf = 0; nf < NF; nf++)
                acc[nf] = mfma16(a, Bf[kk][nf], acc[nf]);
        }
        const int n = n0 + nl;
        const int gy = y0 + fr * 4 + g;
        #pragma unroll
        for (int nf = 0; nf < NF; nf++) {
            const int co = nf * 16 + p;
            #pragma unroll
            for (int r = 0; r < 4; r++) {
                const int gx = x0 + fc * 4 + r;
                const int idx = ((n * IMG + gy) * IMG + gx) * COUT + co;
                float vv = acc[nf][r] + bv_[nf];
                if constexpr (ADD_RES) vv += bf2f(res[idx]);
                out[idx] = f2bf(vv);
            }
        }
    }
}

// ---------------------------------------------------------------------------
// maxpool 3x3 s2 p1, bf16 -> bf16
// ---------------------------------------------------------------------------
template<int S, int CO>
__global__ __launch_bounds__(256) void k_pool_b(
    const u16* __restrict__ in, u16* __restrict__ out)
{
    constexpr int PS = S / 2;
    const int idx = blockIdx.x * 256 + threadIdx.x;
    int c8 = idx % (CO / 8); int r = idx / (CO / 8);
    const int px = r % PS; r /= PS;
    const int py = r % PS; const int n = r / PS;
    if (n >= 2048) return;
    float m[8];
    #pragma unroll
    for (int j = 0; j < 8; j++) m[j] = -3e38f;
    #pragma unroll
    for (int dy = 0; dy < 3; dy++) {
        const int y = 2 * py - 1 + dy;
        if ((unsigned)y >= (unsigned)S) continue;
        #pragma unroll
        for (int dx = 0; dx < 3; dx++) {
            const int x = 2 * px - 1 + dx;
            if ((unsigned)x >= (unsigned)S) continue;
            u16x8 v = *(const u16x8*)&in[((n * S + y) * S + x) * CO + c8 * 8];
            #pragma unroll
            for (int j = 0; j < 8; j++) m[j] = fmaxf(m[j], bf2f(v[j]));
        }
    }
    u16x8 o;
    #pragma unroll
    for (int j = 0; j < 8; j++) o[j] = f2bf(m[j]);
    *(u16x8*)&out[((n * PS + py) * PS + px) * CO + c8 * 8] = o;
}

// ---------------------------------------------------------------------------
// GEMM: out[M,N] = op(A[M,K]) @ B[N,K]^T + bias. 64x64 tile, Kc=64.
// ---------------------------------------------------------------------------
template<bool GATHER_B, bool RELU_A, bool RELU_OUT, bool TWO_BIAS, bool ABF16>
__global__ __launch_bounds__(256) void k_gemm(
    const void* __restrict__ Av, const float* __restrict__ Bm,
    const float* __restrict__ b1, const float* __restrict__ b2,
    float* __restrict__ out, int M, int N, int K)
{
    __shared__ __align__(16) float aL[64*72];
    __shared__ __align__(16) float bL[64*72];
    const int tid = threadIdx.x;
    const int nb = N >> 6;
    const int m0 = (blockIdx.x / nb) << 6;
    const int n0 = (blockIdx.x % nb) << 6;
    const int mt = tid & 15, nt = tid >> 4;
    f4 acc[4] = {f4z(),f4z(),f4z(),f4z()};
    for (int kc = 0; kc < K; kc += 64) {
        __syncthreads();
        #pragma unroll
        for (int i = 0; i < 16; i++) {
            int flat = i*256 + tid;
            int kk = flat & 63, mm = flat >> 6;
            float av;
            if constexpr (ABF16)
                av = bf2f(((const u16*)Av)[(m0+mm)*K + kc+kk]);
            else
                av = ((const float*)Av)[(m0+mm)*K + kc+kk];
            if (RELU_A) av = fmaxf(av, 0.f);
            aL[kk*72 + mm] = av;
            int kg = kc + kk;
            float bv;
            if constexpr (GATHER_B)
                bv = Bm[(n0+mm)*K + (kg & 31)*64 + (kg >> 5)];
            else
                bv = Bm[(n0+mm)*K + kg];
            bL[kk*72 + mm] = bv;
        }
        __syncthreads();
        #pragma unroll
        for (int k = 0; k < 64; k++) {
            f4 a4 = *(const f4*)&aL[k*72 + mt*4];
            f4 b4 = *(const f4*)&bL[k*72 + nt*4];
            acc[0] += a4.x * b4;
            acc[1] += a4.y * b4;
            acc[2] += a4.z * b4;
            acc[3] += a4.w * b4;
        }
    }
    f4 bias = *(const f4*)&b1[n0 + nt*4];
    if constexpr (TWO_BIAS) bias += *(const f4*)&b2[n0 + nt*4];
    #pragma unroll
    for (int mi = 0; mi < 4; mi++) {
        f4 v = acc[mi] + bias;
        if (RELU_OUT) {
            v.x=fmaxf(v.x,0.f); v.y=fmaxf(v.y,0.f);
            v.z=fmaxf(v.z,0.f); v.w=fmaxf(v.w,0.f);
        }
        *(f4*)&out[(m0 + mt*4 + mi)*N + n0 + nt*4] = v;
    }
}

// ---------------------------------------------------------------------------
// k_lstm16 (validated round 8, unchanged)
// ---------------------------------------------------------------------------
__global__ __launch_bounds__(256) void k_lstm16(
    const float* __restrict__ pre, const int* __restrict__ done,
    const float* __restrict__ h0, const float* __restrict__ c0,
    const float* __restrict__ whh,
    u32* __restrict__ hx, unsigned* __restrict__ cnt,
    float* __restrict__ out)
{
    __shared__ __align__(16) u16 hBhi[32*264];
    __shared__ __align__(16) u16 hBlo[32*264];
    __shared__ float gL[4*32*17];
    const int tid = threadIdx.x;
    const int wg  = blockIdx.x;
    const int j0  = wg * 16;
    const int lane = tid & 63, w = tid >> 6;
    const int p = lane & 15, g4 = lane >> 4;

    s8v Bhi[8], Blo[8];
    {
        const float* wr = &whh[(w*256 + j0 + p) * 256];
        #pragma unroll
        for (int kk = 0; kk < 8; kk++) {
            const float* wp = &wr[kk*32 + g4*8];
            f4 w0 = *(const f4*)&wp[0];
            f4 w1 = *(const f4*)&wp[4];
            s8v bh, bl;
            #pragma unroll
            for (int e = 0; e < 4; e++) {
                u16 h0_ = f2bf(w0[e]); u16 l0_ = f2bf(w0[e] - bf2f(h0_));
                u16 h1_ = f2bf(w1[e]); u16 l1_ = f2bf(w1[e] - bf2f(h1_));
                bh[e] = (short)h0_; bh[e+4] = (short)h1_;
                bl[e] = (short)l0_; bl[e+4] = (short)l1_;
            }
            Bhi[kk] = bh; Blo[kk] = bl;
        }
    }
    const int sb = tid >> 3, ss = tid & 7;
    const int jl2 = tid & 7;
    float cr0 = c0[sb*256 + j0 + jl2*2];
    float cr1 = c0[sb*256 + j0 + jl2*2 + 1];

    for (int st = 0; st < 64; st++) {
        const float mm = (done[st*32 + sb] != 0) ? 0.f : 1.f;
        float preR[8];
        #pragma unroll
        for (int r = 0; r < 4; r++) {
            preR[r]   = pre[(st*32 + g4*4 + r)*1024 + w*256 + j0 + p];
            preR[4+r] = pre[(st*32 + 16 + g4*4 + r)*1024 + w*256 + j0 + p];
        }
        if (st == 0) {
            const float* hp = &h0[sb*256 + ss*32];
            #pragma unroll
            for (int i = 0; i < 32; i++) {
                float v = hp[i] * mm;
                u16 hi = f2bf(v);
                u16 lo = f2bf(v - bf2f(hi));
                hBhi[sb*264 + ss*32 + i] = hi;
                hBlo[sb*264 + ss*32 + i] = lo;
            }
        } else {
            const u64* src = (const u64*)&hx[(st & 1)*8192 + sb*256];
            u64 rh[8], rl[8];
            if (mm != 0.f) {
                #pragma unroll
                for (int i = 0; i < 8; i++)
                    rh[i] = __hip_atomic_load(&src[ss*8 + i], __ATOMIC_RELAXED, __HIP_MEMORY_SCOPE_AGENT);
                #pragma unroll
                for (int i = 0; i < 8; i++)
                    rl[i] = __hip_atomic_load(&src[64 + ss*8 + i], __ATOMIC_RELAXED, __HIP_MEMORY_SCOPE_AGENT);
            } else {
                #pragma unroll
                for (int i = 0; i < 8; i++) { rh[i] = 0; rl[i] = 0; }
            }
            #pragma unroll
            for (int qq = 0; qq < 4; qq++) {
                u32x4 a = {lo32(rh[qq*2]), hi32(rh[qq*2]), lo32(rh[qq*2+1]), hi32(rh[qq*2+1])};
                u32x4 b = {lo32(rl[qq*2]), hi32(rl[qq*2]), lo32(rl[qq*2+1]), hi32(rl[qq*2+1])};
                *(u32x4*)&hBhi[sb*264 + ss*32 + qq*8] = a;
                *(u32x4*)&hBlo[sb*264 + ss*32 + qq*8] = b;
            }
        }
        __syncthreads();
        f4 acc0 = f4z(), acc1 = f4z();
        #pragma unroll
        for (int kk = 0; kk < 8; kk++) {
            const int o0 = p*264 + kk*32 + g4*8;
            const int o1 = (16 + p)*264 + kk*32 + g4*8;
            s8v ah0 = *(const s8v*)&hBhi[o0];
            s8v al0 = *(const s8v*)&hBlo[o0];
            s8v ah1 = *(const s8v*)&hBhi[o1];
            s8v al1 = *(const s8v*)&hBlo[o1];
            acc0 = mfma16(ah0, Bhi[kk], acc0);
            acc0 = mfma16(al0, Bhi[kk], acc0);
            acc0 = mfma16(ah0, Blo[kk], acc0);
            acc1 = mfma16(ah1, Bhi[kk], acc1);
            acc1 = mfma16(al1, Bhi[kk], acc1);
            acc1 = mfma16(ah1, Blo[kk], acc1);
        }
        #pragma unroll
        for (int r = 0; r < 4; r++) {
            gL[(w*32 + g4*4 + r)*17 + p]      = acc0[r] + preR[r];
            gL[(w*32 + 16 + g4*4 + r)*17 + p] = acc1[r] + preR[4+r];
        }
        __syncthreads();
        {
            float hv[2];
            float cr[2] = {cr0, cr1};
            #pragma unroll
            for (int q = 0; q < 2; q++) {
                const int jl = jl2*2 + q;
                const float iv = gL[(0*32 + sb)*17 + jl];
                const float fv = gL[(1*32 + sb)*17 + jl];
                const float gv = gL[(2*32 + sb)*17 + jl];
                const float ov = gL[(3*32 + sb)*17 + jl];
                const float c = sigm(fv)*(cr[q]*mm) + sigm(iv)*tanhf(gv);
                cr[q] = c;
                const float h = sigm(ov)*tanhf(c);
                out[(st*32 + sb)*256 + j0 + jl] = h;
                hv[q] = h;
            }
            cr0 = cr[0]; cr1 = cr[1];
            u16 h0b = f2bf(hv[0]);
            u16 h1b = f2bf(hv[1]);
            u32 hp = ((u32)h1b << 16) | (u32)h0b;
            u32 lp = ((u32)f2bf(hv[1] - bf2f(h1b)) << 16) | (u32)f2bf(hv[0] - bf2f(h0b));
            u32* dst = &hx[((st+1) & 1)*8192 + sb*256];
            __hip_atomic_store(&dst[wg*8 + jl2], hp, __ATOMIC_RELAXED, __HIP_MEMORY_SCOPE_AGENT);
            __hip_atomic_store(&dst[128 + wg*8 + jl2], lp, __ATOMIC_RELAXED, __HIP_MEMORY_SCOPE_AGENT);
        }
        __syncthreads();
        if (st < 63) {
            if (tid == 0) {
                __hip_atomic_fetch_add(&cnt[st], 1u, __ATOMIC_RELAXED, __HIP_MEMORY_SCOPE_AGENT);
                while (__hip_atomic_fetch_add(&cnt[st], 0u, __ATOMIC_RELAXED, __HIP_MEMORY_SCOPE_AGENT) < 16u)
                    __builtin_amdgcn_s_sleep(1);
            }
            __syncthreads();
        }
    }
}

// ---------------------------------------------------------------------------
extern "C" void kernel_launch(void* const* d_in, const int* in_sizes, int n_in,
                              void* d_out, int out_size, void* d_ws, size_t ws_size,
                              hipStream_t stream)
{
    (void)in_sizes; (void)n_in; (void)out_size; (void)ws_size;
    const float* x   = (const float*)d_in[0];
    const int*   dn  = (const int*)  d_in[1];
    const float* h0  = (const float*)d_in[2];
    const float* c0  = (const float*)d_in[3];
    const float* cw0 = (const float*)d_in[4];
    const float* cb0 = (const float*)d_in[5];
    const float* rw0 = (const float*)d_in[6];
    const float* rb0 = (const float*)d_in[7];
    const float* cw1 = (const float*)d_in[8];
    const float* cb1 = (const float*)d_in[9];
    const float* rw1 = (const float*)d_in[10];
    const float* rb1 = (const float*)d_in[11];
    const float* cw2 = (const float*)d_in[12];
    const float* cb2 = (const float*)d_in[13];
    const float* rw2 = (const float*)d_in[14];
    const float* rb2 = (const float*)d_in[15];
    const float* fcw = (const float*)d_in[16];
    const float* fcb = (const float*)d_in[17];
    const float* wih = (const float*)d_in[18];
    const float* whh = (const float*)d_in[19];
    const float* bih = (const float*)d_in[20];
    const float* bhh = (const float*)d_in[21];

    char* wsb = (char*)d_ws;
    // [0,64M): P0 / {P1,T1} / {P2,T2}   [64M,128M): T0, then C1 low half / C2
    // C1 = [64M,192M)   hid/preb/hx in [96M,128M) after convs   wbuf [192M,193M)
    u16* P0 = (u16*)wsb;                           // 64MB
    u16* T0 = (u16*)(wsb + 67108864ull);           // 64MB (seq0 only)
    u16* C1 = (u16*)(wsb + 67108864ull);           // 128MB [64,192) (T0 dead)
    u16* P1 = (u16*)wsb;                           // 32MB
    u16* T1 = (u16*)(wsb + 33554432ull);           // 32MB
    u16* C2 = (u16*)(wsb + 67108864ull);           // 32MB [64,96) (C1 dead)
    u16* P2 = (u16*)wsb;                           // 8MB
    u16* T2 = (u16*)(wsb + 8388608ull);            // 8MB
    float* hid  = (float*)(wsb + 100663296ull);    // 2MB  (96M)
    float* preb = (float*)(wsb + 104857600ull);    // 8MB  (100M)
    u32*   hx   = (u32*)  (wsb + 117440512ull);    // (112M)
    unsigned* cnt = (unsigned*)(wsb + 117506048ull);
    u16* wb   = (u16*)(wsb + 201326592ull);        // 410KB (192M)

    // weight prep (all conv layers -> bf16 fragment layout)
    k_prep<<<dim3(388), dim3(256), 0, stream>>>(cw0, rw0, cw1, rw1, cw2, rw2, wb);
    // seq0
    k_conv0_mfma<<<dim3(8192), dim3(256), 0, stream>>>(x, wb + WB_C0, cb0, P0);
    k_conv_bf<16,16,32,16,32,1,true,false><<<dim3(4096), dim3(256), 0, stream>>>(P0, wb+WB_RW0,        rb0,    nullptr, T0);
    k_conv_bf<16,16,32,16,32,1,true,true ><<<dim3(4096), dim3(256), 0, stream>>>(T0, wb+WB_RW0+2688,   rb0+16, P0,      P0);
    k_conv_bf<16,16,32,16,32,1,true,false><<<dim3(4096), dim3(256), 0, stream>>>(P0, wb+WB_RW0+2*2688, rb0+32, nullptr, T0);
    k_conv_bf<16,16,32,16,32,1,true,true ><<<dim3(4096), dim3(256), 0, stream>>>(T0, wb+WB_RW0+3*2688, rb0+48, P0,      P0);
    // seq1
    k_conv_bf<16,32,32,16,32,1,false,false><<<dim3(4096), dim3(256), 0, stream>>>(P0, wb+WB_CW1, cb1, nullptr, C1);
    k_pool_b<32,32><<<dim3(8192), dim3(256), 0, stream>>>(C1, P1);
    k_conv_bf<32,32,16,16,16,1,true,false><<<dim3(2048), dim3(256), 0, stream>>>(P1, wb+WB_RW1,        rb1,    nullptr, T1);
    k_conv_bf<32,32,16,16,16,1,true,true ><<<dim3(2048), dim3(256), 0, stream>>>(T1, wb+WB_RW1+9472,   rb1+32, P1,      P1);
    k_conv_bf<32,32,16,16,16,1,true,false><<<dim3(2048), dim3(256), 0, stream>>>(P1, wb+WB_RW1+2*9472, rb1+64, nullptr, T1);
    k_conv_bf<32,32,16,16,16,1,true,true ><<<dim3(2048), dim3(256), 0, stream>>>(T1, wb+WB_RW1+3*9472, rb1+96, P1,      P1);
    // seq2
    k_conv_bf<32,32,16,16,16,1,false,false><<<dim3(2048), dim3(256), 0, stream>>>(P1, wb+WB_CW2, cb2, nullptr, C2);
    k_pool_b<16,32><<<dim3(2048), dim3(256), 0, stream>>>(C2, P2);
    k_conv_bf<32,32,8,8,8,4,true,false><<<dim3(512), dim3(256), 0, stream>>>(P2, wb+WB_RW2,        rb2,    nullptr, T2);
    k_conv_bf<32,32,8,8,8,4,true,true ><<<dim3(512), dim3(256), 0, stream>>>(T2, wb+WB_RW2+9472,   rb2+32, P2,      P2);
    k_conv_bf<32,32,8,8,8,4,true,false><<<dim3(512), dim3(256), 0, stream>>>(P2, wb+WB_RW2+2*9472, rb2+64, nullptr, T2);
    k_conv_bf<32,32,8,8,8,4,true,true ><<<dim3(512), dim3(256), 0, stream>>>(T2, wb+WB_RW2+3*9472, rb2+96, P2,      P2);
    // FC (bf16 A) + LSTM input projection + recurrent LSTM
    k_gemm<true,true,true,false,true ><<<dim3(128), dim3(256), 0, stream>>>(P2,  fcw, fcb, nullptr, hid,  2048, 256, 2048);
    k_gemm<false,false,false,true,false><<<dim3(512), dim3(256), 0, stream>>>(hid, wih, bih, bhh,   preb, 2048, 1024, 256);
    hipMemsetAsync(cnt, 0, 256, stream);
    k_lstm16<<<dim3(16), dim3(256), 0, stream>>>(preb, dn, h0, c0, whh, hx, cnt, (float*)d_out);
}